// Round 3
// baseline (1055.377 us; speedup 1.0000x reference)
//
#include <hip/hip_runtime.h>

static constexpr int D  = 1024;
static constexpr int NH = 16;
static constexpr int DH = 64;

// ---------------------------------------------------------------------------
// SGEMM: C[M,1024] = A[M,1024] @ B[1024,1024] + bias  (fp32, vector ALU)
// Tile 128x128, BK=8, 256 threads, 8x8 per thread (split 4+4 micro-tiles).
// ---------------------------------------------------------------------------
__global__ __launch_bounds__(256) void sgemm_bias_kernel(
    const float* __restrict__ A, const float* __restrict__ B,
    const float* __restrict__ bias, float* __restrict__ C)
{
    const int K = 1024, N = 1024;
    __shared__ float As[8][128];
    __shared__ float Bs[8][128];

    const int tid = threadIdx.x;
    const int bm = blockIdx.y, bn = blockIdx.x;

    const int arow = tid >> 1;
    const int acol = (tid & 1) << 2;
    const int brow = tid >> 5;
    const int bcol = (tid & 31) << 2;

    const float* Ap = A + (size_t)(bm * 128 + arow) * K + acol;
    const float* Bp = B + (size_t)brow * N + bn * 128 + bcol;

    const int tm = (tid >> 4) << 2;
    const int tn = (tid & 15) << 2;

    float acc[8][8];
#pragma unroll
    for (int i = 0; i < 8; ++i)
#pragma unroll
        for (int j = 0; j < 8; ++j) acc[i][j] = 0.f;

    float4 av = *(const float4*)Ap;
    float4 bv = *(const float4*)Bp;

    for (int k0 = 0; k0 < K; k0 += 8) {
        __syncthreads();
        As[acol + 0][arow] = av.x;
        As[acol + 1][arow] = av.y;
        As[acol + 2][arow] = av.z;
        As[acol + 3][arow] = av.w;
        *(float4*)&Bs[brow][bcol] = bv;
        __syncthreads();
        if (k0 + 8 < K) {
            av = *(const float4*)(Ap + k0 + 8);
            bv = *(const float4*)(Bp + (size_t)(k0 + 8) * N);
        }
#pragma unroll
        for (int kk = 0; kk < 8; ++kk) {
            float4 a0 = *(const float4*)&As[kk][tm];
            float4 a1 = *(const float4*)&As[kk][tm + 64];
            float4 b0 = *(const float4*)&Bs[kk][tn];
            float4 b1 = *(const float4*)&Bs[kk][tn + 64];
            float ar[8] = {a0.x, a0.y, a0.z, a0.w, a1.x, a1.y, a1.z, a1.w};
            float br[8] = {b0.x, b0.y, b0.z, b0.w, b1.x, b1.y, b1.z, b1.w};
#pragma unroll
            for (int i = 0; i < 8; ++i)
#pragma unroll
                for (int j = 0; j < 8; ++j)
                    acc[i][j] = fmaf(ar[i], br[j], acc[i][j]);
        }
    }

#pragma unroll
    for (int i = 0; i < 8; ++i) {
        const int row = bm * 128 + ((i < 4) ? (tm + i) : (64 + tm + (i - 4)));
#pragma unroll
        for (int jb = 0; jb < 2; ++jb) {
            const int col = bn * 128 + (jb ? (64 + tn) : tn);
            float4 bb = *(const float4*)&bias[col];
            float4 o;
            o.x = acc[i][jb * 4 + 0] + bb.x;
            o.y = acc[i][jb * 4 + 1] + bb.y;
            o.z = acc[i][jb * 4 + 2] + bb.z;
            o.w = acc[i][jb * 4 + 3] + bb.w;
            *(float4*)&C[(size_t)row * N + col] = o;
        }
    }
}

// ---------------------------------------------------------------------------
// PROBE: split-bf16 MFMA GEMM, C = A@B + bias (fp32 in/out via hi/lo bf16).
// Writes to dead workspace only; correctness probed by check_kernel below.
// Tile 128x128, BK=32, 256 threads = 4 waves (2x2), 64x64 per wave,
// mfma_f32_16x16x32_bf16, 3 products (hh, hl, lh), fp32 accum.
// LDS: Ah/Al[row][k] and Bh/Bl[col][k], k-pitch 40 (80B: 16B-aligned rows,
// 2-way max bank aliasing on ds_read_b128 = free per m136).
// ---------------------------------------------------------------------------
using bf16x8 = __attribute__((ext_vector_type(8))) __bf16;
using f32x4  = __attribute__((ext_vector_type(4))) float;

__global__ __launch_bounds__(256) void mfma_probe_gemm(
    const float* __restrict__ A, const float* __restrict__ B,
    const float* __restrict__ bias, float* __restrict__ C)
{
    __shared__ __bf16 Ah[128][40], Al[128][40];
    __shared__ __bf16 Bh[128][40], Bl[128][40];   // stored [n-col][k]

    const int tid = threadIdx.x;
    const int bm = blockIdx.y, bn = blockIdx.x;
    const int wave = tid >> 6, lane = tid & 63;
    const int wr = wave >> 1, wc = wave & 1;
    const int li = lane & 15, g = lane >> 4;

    const int ar = tid >> 1, ac = (tid & 1) << 4;          // A: 2 thr/row, 16 f
    const int br = tid >> 3, bc = (tid & 7) << 4;          // B: 8 thr/row, 16 f

    f32x4 acc[4][4];
#pragma unroll
    for (int m = 0; m < 4; ++m)
#pragma unroll
        for (int n = 0; n < 4; ++n) acc[m][n] = (f32x4)0.f;

    for (int k0 = 0; k0 < 1024; k0 += 32) {
        __syncthreads();
        // ---- stage A[128][32] hi/lo ----
        {
            const float* ap = A + (size_t)(bm * 128 + ar) * 1024 + k0 + ac;
#pragma unroll
            for (int h = 0; h < 2; ++h) {                  // two 8-float groups
                float4 v0 = *(const float4*)(ap + h * 8);
                float4 v1 = *(const float4*)(ap + h * 8 + 4);
                float f[8] = {v0.x, v0.y, v0.z, v0.w, v1.x, v1.y, v1.z, v1.w};
                bf16x8 vh, vl;
#pragma unroll
                for (int e = 0; e < 8; ++e) {
                    __bf16 hi = (__bf16)f[e];
                    vh[e] = hi;
                    vl[e] = (__bf16)(f[e] - (float)hi);
                }
                *(bf16x8*)&Ah[ar][ac + h * 8] = vh;
                *(bf16x8*)&Al[ar][ac + h * 8] = vl;
            }
        }
        // ---- stage B[32][128] hi/lo, transposed into [col][k] ----
        {
            const float* bp = B + (size_t)(k0 + br) * 1024 + bn * 128 + bc;
#pragma unroll
            for (int q = 0; q < 4; ++q) {
                float4 v = *(const float4*)(bp + q * 4);
                float f[4] = {v.x, v.y, v.z, v.w};
#pragma unroll
                for (int e = 0; e < 4; ++e) {
                    __bf16 hi = (__bf16)f[e];
                    Bh[bc + q * 4 + e][br] = hi;
                    Bl[bc + q * 4 + e][br] = (__bf16)(f[e] - (float)hi);
                }
            }
        }
        __syncthreads();

        // ---- fragments + 48 MFMA ----
        bf16x8 fah[4], fal[4], fbh[4], fbl[4];
#pragma unroll
        for (int m = 0; m < 4; ++m) {
            fah[m] = *(const bf16x8*)&Ah[wr * 64 + m * 16 + li][g * 8];
            fal[m] = *(const bf16x8*)&Al[wr * 64 + m * 16 + li][g * 8];
        }
#pragma unroll
        for (int n = 0; n < 4; ++n) {
            fbh[n] = *(const bf16x8*)&Bh[wc * 64 + n * 16 + li][g * 8];
            fbl[n] = *(const bf16x8*)&Bl[wc * 64 + n * 16 + li][g * 8];
        }
#pragma unroll
        for (int m = 0; m < 4; ++m)
#pragma unroll
            for (int n = 0; n < 4; ++n) {
                acc[m][n] = __builtin_amdgcn_mfma_f32_16x16x32_bf16(fah[m], fbh[n], acc[m][n], 0, 0, 0);
                acc[m][n] = __builtin_amdgcn_mfma_f32_16x16x32_bf16(fah[m], fbl[n], acc[m][n], 0, 0, 0);
                acc[m][n] = __builtin_amdgcn_mfma_f32_16x16x32_bf16(fal[m], fbh[n], acc[m][n], 0, 0, 0);
            }
    }

    // ---- epilogue: C/D layout col=lane&15, row=(lane>>4)*4+e (m89-verified) ----
#pragma unroll
    for (int m = 0; m < 4; ++m)
#pragma unroll
        for (int n = 0; n < 4; ++n) {
            const int col = bn * 128 + wc * 64 + n * 16 + li;
            const float bb = bias[col];
#pragma unroll
            for (int e = 0; e < 4; ++e) {
                const int row = bm * 128 + wr * 64 + m * 16 + g * 4 + e;
                C[(size_t)row * 1024 + col] = acc[m][n][e] + bb;
            }
        }
}

// ---------------------------------------------------------------------------
// Layout checker with timing side-channel: if |X-Y| > tol anywhere, mismatching
// threads run a ~3ms dependent-FMA chain -> visible in total time / top-5.
// Split-bf16 true error ~1e-5; tol=1e-3; layout bugs give O(0.5) diffs.
// ---------------------------------------------------------------------------
__global__ __launch_bounds__(256) void check_kernel(
    const float* __restrict__ X, const float* __restrict__ Y, float* flag)
{
    const size_t i = ((size_t)blockIdx.x * 256 + threadIdx.x) * 4;
    float4 x = *(const float4*)&X[i];
    float4 y = *(const float4*)&Y[i];
    float d = fmaxf(fmaxf(fabsf(x.x - y.x), fabsf(x.y - y.y)),
                    fmaxf(fabsf(x.z - y.z), fabsf(x.w - y.w)));
    if (d > 1e-3f) {
        float z = d;
        for (int it = 0; it < 2000000; ++it) z = fmaf(z, 1.0000001f, 1e-7f);
        if (z == 123.456f) atomicAdd(flag, 1.f);   // never true; keeps chain live
    }
}

// ---------------------------------------------------------------------------
// Flash attention (fp32). Grid (Nq/64, H). Block 256 threads.
// ---------------------------------------------------------------------------
__global__ __launch_bounds__(256) void attn_kernel(
    const float* __restrict__ Q, const float* __restrict__ Kp,
    const float* __restrict__ Vp, float* __restrict__ ctx, int Nv)
{
    __shared__ float Qs[DH][68];
    __shared__ float Ks[DH][68];
    __shared__ float Vs[64][68];
    __shared__ float Ps[64][68];

    const int tid = threadIdx.x;
    const int h  = blockIdx.y;
    const int q0 = blockIdx.x * 64;
    const int tr = tid >> 4;
    const int tc = tid & 15;

#pragma unroll
    for (int it = 0; it < 4; ++it) {
        int idx = tid + 256 * it;
        int row = idx >> 4;
        int d4  = (idx & 15) << 2;
        float4 v = *(const float4*)&Q[(size_t)(q0 + row) * D + h * DH + d4];
        Qs[d4 + 0][row] = v.x * 0.125f;
        Qs[d4 + 1][row] = v.y * 0.125f;
        Qs[d4 + 2][row] = v.z * 0.125f;
        Qs[d4 + 3][row] = v.w * 0.125f;
    }

    float m[4], l[4], O[4][4];
#pragma unroll
    for (int i = 0; i < 4; ++i) {
        m[i] = -1e30f; l[i] = 0.f;
#pragma unroll
        for (int j = 0; j < 4; ++j) O[i][j] = 0.f;
    }

    for (int kt = 0; kt < Nv; kt += 64) {
        __syncthreads();
#pragma unroll
        for (int it = 0; it < 4; ++it) {
            int idx = tid + 256 * it;
            int row = idx >> 4;
            int d4  = (idx & 15) << 2;
            float4 kv = *(const float4*)&Kp[(size_t)(kt + row) * D + h * DH + d4];
            Ks[d4 + 0][row] = kv.x;
            Ks[d4 + 1][row] = kv.y;
            Ks[d4 + 2][row] = kv.z;
            Ks[d4 + 3][row] = kv.w;
            float4 vv = *(const float4*)&Vp[(size_t)(kt + row) * D + h * DH + d4];
            *(float4*)&Vs[row][d4] = vv;
        }
        __syncthreads();

        float s[4][4];
#pragma unroll
        for (int i = 0; i < 4; ++i)
#pragma unroll
            for (int j = 0; j < 4; ++j) s[i][j] = 0.f;

        for (int d = 0; d < DH; ++d) {
            float4 qv = *(const float4*)&Qs[d][tr * 4];
            float4 kv = *(const float4*)&Ks[d][tc * 4];
            float qa[4] = {qv.x, qv.y, qv.z, qv.w};
            float ka[4] = {kv.x, kv.y, kv.z, kv.w};
#pragma unroll
            for (int i = 0; i < 4; ++i)
#pragma unroll
                for (int j = 0; j < 4; ++j)
                    s[i][j] = fmaf(qa[i], ka[j], s[i][j]);
        }

        float rm[4];
#pragma unroll
        for (int i = 0; i < 4; ++i)
            rm[i] = fmaxf(fmaxf(s[i][0], s[i][1]), fmaxf(s[i][2], s[i][3]));
#pragma unroll
        for (int off = 1; off < 16; off <<= 1)
#pragma unroll
            for (int i = 0; i < 4; ++i)
                rm[i] = fmaxf(rm[i], __shfl_xor(rm[i], off, 64));

        float al[4], rs[4];
#pragma unroll
        for (int i = 0; i < 4; ++i) {
            float mn = fmaxf(m[i], rm[i]);
            al[i] = __expf(m[i] - mn);
            m[i] = mn;
            float acc = 0.f;
#pragma unroll
            for (int j = 0; j < 4; ++j) {
                s[i][j] = __expf(s[i][j] - mn);
                acc += s[i][j];
            }
            rs[i] = acc;
        }
#pragma unroll
        for (int off = 1; off < 16; off <<= 1)
#pragma unroll
            for (int i = 0; i < 4; ++i)
                rs[i] += __shfl_xor(rs[i], off, 64);
#pragma unroll
        for (int i = 0; i < 4; ++i) {
            l[i] = l[i] * al[i] + rs[i];
#pragma unroll
            for (int j = 0; j < 4; ++j) O[i][j] *= al[i];
        }

#pragma unroll
        for (int i = 0; i < 4; ++i)
#pragma unroll
            for (int j = 0; j < 4; ++j)
                Ps[tc * 4 + j][tr * 4 + i] = s[i][j];
        __syncthreads();

        for (int k = 0; k < 64; ++k) {
            float4 pv = *(const float4*)&Ps[k][tr * 4];
            float4 vv = *(const float4*)&Vs[k][tc * 4];
            float pa[4] = {pv.x, pv.y, pv.z, pv.w};
            float va[4] = {vv.x, vv.y, vv.z, vv.w};
#pragma unroll
            for (int i = 0; i < 4; ++i)
#pragma unroll
                for (int j = 0; j < 4; ++j)
                    O[i][j] = fmaf(pa[i], va[j], O[i][j]);
        }
    }

#pragma unroll
    for (int i = 0; i < 4; ++i) {
        const int row = q0 + tr * 4 + i;
        const float inv = 1.f / l[i];
        float4 o;
        o.x = O[i][0] * inv; o.y = O[i][1] * inv;
        o.z = O[i][2] * inv; o.w = O[i][3] * inv;
        *(float4*)&ctx[(size_t)row * D + h * DH + tc * 4] = o;
    }
}

// ---------------------------------------------------------------------------
// Fused residual + LN(1e-12) + LN(1e-5). One block per row.
// ---------------------------------------------------------------------------
__global__ __launch_bounds__(256) void resid_dual_ln_kernel(
    const float* __restrict__ att, const float* __restrict__ resid,
    const float* __restrict__ g1, const float* __restrict__ b1,
    const float* __restrict__ g2, const float* __restrict__ b2,
    float* __restrict__ out)
{
    const int row = blockIdx.x;
    const int tid = threadIdx.x;
    const int c = tid << 2;
    const size_t base = (size_t)row * D + c;

    float4 a = *(const float4*)&att[base];
    float4 r = *(const float4*)&resid[base];
    float t[4] = {a.x + r.x, a.y + r.y, a.z + r.z, a.w + r.w};

    __shared__ float red[8];
    const int wid = tid >> 6, lane = tid & 63;

    float s = t[0] + t[1] + t[2] + t[3];
    float sq = t[0]*t[0] + t[1]*t[1] + t[2]*t[2] + t[3]*t[3];
#pragma unroll
    for (int off = 1; off < 64; off <<= 1) {
        s  += __shfl_xor(s, off, 64);
        sq += __shfl_xor(sq, off, 64);
    }
    if (lane == 0) { red[wid] = s; red[4 + wid] = sq; }
    __syncthreads();
    s  = red[0] + red[1] + red[2] + red[3];
    sq = red[4] + red[5] + red[6] + red[7];

    float mu  = s * (1.f / D);
    float var = sq * (1.f / D) - mu * mu;
    float rr  = rsqrtf(var + 1e-12f);

    float4 G1 = *(const float4*)&g1[c];
    float4 B1 = *(const float4*)&b1[c];
    float g1a[4] = {G1.x, G1.y, G1.z, G1.w};
    float b1a[4] = {B1.x, B1.y, B1.z, B1.w};
    float v[4];
#pragma unroll
    for (int j = 0; j < 4; ++j) v[j] = (t[j] - mu) * rr * g1a[j] + b1a[j];

    float s2 = v[0] + v[1] + v[2] + v[3];
    float q2 = v[0]*v[0] + v[1]*v[1] + v[2]*v[2] + v[3]*v[3];
#pragma unroll
    for (int off = 1; off < 64; off <<= 1) {
        s2 += __shfl_xor(s2, off, 64);
        q2 += __shfl_xor(q2, off, 64);
    }
    __syncthreads();
    if (lane == 0) { red[wid] = s2; red[4 + wid] = q2; }
    __syncthreads();
    s2 = red[0] + red[1] + red[2] + red[3];
    q2 = red[4] + red[5] + red[6] + red[7];

    float mu2  = s2 * (1.f / D);
    float var2 = q2 * (1.f / D) - mu2 * mu2;
    float r2   = rsqrtf(var2 + 1e-5f);

    float4 G2 = *(const float4*)&g2[c];
    float4 B2 = *(const float4*)&b2[c];
    float g2a[4] = {G2.x, G2.y, G2.z, G2.w};
    float b2a[4] = {B2.x, B2.y, B2.z, B2.w};
    float4 o;
    float oo[4];
#pragma unroll
    for (int j = 0; j < 4; ++j) oo[j] = (v[j] - mu2) * r2 * g2a[j] + b2a[j];
    o.x = oo[0]; o.y = oo[1]; o.z = oo[2]; o.w = oo[3];
    *(float4*)&out[base] = o;
}

// ---------------------------------------------------------------------------
// ws layout (floats): Qp[Nq*D] | Kp[Nv*D] | Vp[Nv*D] | ctx[Nq*D] | probeC[Nq*D] | flag
// aliases: att=Qp (Q dead after attn), x2=ctx (ctx dead after Wo GEMM)
// ---------------------------------------------------------------------------
extern "C" void kernel_launch(void* const* d_in, const int* in_sizes, int n_in,
                              void* d_out, int out_size, void* d_ws, size_t ws_size,
                              hipStream_t stream)
{
    const float* qf  = (const float*)d_in[0];
    const float* vf  = (const float*)d_in[1];
    const float* Wq  = (const float*)d_in[2];
    const float* bq  = (const float*)d_in[3];
    const float* Wk  = (const float*)d_in[4];
    const float* bk  = (const float*)d_in[5];
    const float* Wv  = (const float*)d_in[6];
    const float* bv  = (const float*)d_in[7];
    const float* Wo  = (const float*)d_in[8];
    const float* bo  = (const float*)d_in[9];
    const float* g1  = (const float*)d_in[10];
    const float* b1  = (const float*)d_in[11];
    const float* g2  = (const float*)d_in[12];
    const float* b2  = (const float*)d_in[13];
    const float* Wl  = (const float*)d_in[14];
    const float* bl  = (const float*)d_in[15];

    const int Nq = in_sizes[0] / D;   // 4096
    const int Nv = in_sizes[1] / D;   // 1024

    float* ws  = (float*)d_ws;
    float* Qp  = ws;
    float* Kp  = Qp  + (size_t)Nq * D;
    float* Vp  = Kp  + (size_t)Nv * D;
    float* ctx = Vp  + (size_t)Nv * D;
    float* att = Qp;
    float* x2  = ctx;
    float* probeC = ctx + (size_t)Nq * D;
    float* flag   = probeC + (size_t)Nq * D;

    const size_t need = ((size_t)(2 * Nq + 2 * Nv) * D + (size_t)Nq * D + 16) * sizeof(float);
    const bool do_probe = (ws_size >= need);

    dim3 blk(256);
    sgemm_bias_kernel<<<dim3(8, Nq / 128), blk, 0, stream>>>(qf, Wq, bq, Qp);
    if (do_probe) {
        mfma_probe_gemm<<<dim3(8, Nq / 128), blk, 0, stream>>>(qf, Wq, bq, probeC);
        check_kernel<<<dim3((Nq * D) / 1024), blk, 0, stream>>>(probeC, Qp, flag);
    }
    sgemm_bias_kernel<<<dim3(8, Nv / 128), blk, 0, stream>>>(vf, Wk, bk, Kp);
    sgemm_bias_kernel<<<dim3(8, Nv / 128), blk, 0, stream>>>(vf, Wv, bv, Vp);
    attn_kernel<<<dim3(Nq / 64, NH), blk, 0, stream>>>(Qp, Kp, Vp, ctx, Nv);
    sgemm_bias_kernel<<<dim3(8, Nq / 128), blk, 0, stream>>>(ctx, Wo, bo, att);
    resid_dual_ln_kernel<<<dim3(Nq), blk, 0, stream>>>(att, qf, g1, b1, g2, b2, x2);
    sgemm_bias_kernel<<<dim3(8, Nq / 128), blk, 0, stream>>>(x2, Wl, bl, (float*)d_out);
}

// Round 4
// 906.917 us; speedup vs baseline: 1.1637x; 1.1637x over previous
//
#include <hip/hip_runtime.h>

static constexpr int D  = 1024;
static constexpr int NH = 16;
static constexpr int DH = 64;

using bf16x8 = __attribute__((ext_vector_type(8))) __bf16;
using f32x4  = __attribute__((ext_vector_type(4))) float;

// ---------------------------------------------------------------------------
// Split-bf16 MFMA GEMM (HW-verified round 3): C = A@B + bias, fp32 in/out.
// A = hi+lo bf16 decomposition; 3 MFMA products (hh, hl, lh), fp32 accum.
// Tile 128x128, BK=32, 4 waves (2x2), 64x64 per wave, mfma_f32_16x16x32_bf16.
// C/D layout (m89-verified): col = lane&15, row = (lane>>4)*4 + e.
// ---------------------------------------------------------------------------
__global__ __launch_bounds__(256) void mfma_gemm_bias(
    const float* __restrict__ A, const float* __restrict__ B,
    const float* __restrict__ bias, float* __restrict__ C)
{
    __shared__ alignas(16) __bf16 Ah[128][40], Al[128][40];
    __shared__ alignas(16) __bf16 Bh[128][40], Bl[128][40];   // stored [n-col][k]

    const int tid = threadIdx.x;
    const int bm = blockIdx.y, bn = blockIdx.x;
    const int wave = tid >> 6, lane = tid & 63;
    const int wr = wave >> 1, wc = wave & 1;
    const int li = lane & 15, g = lane >> 4;

    const int ar = tid >> 1, ac = (tid & 1) << 4;
    const int br = tid >> 3, bc = (tid & 7) << 4;

    f32x4 acc[4][4];
#pragma unroll
    for (int m = 0; m < 4; ++m)
#pragma unroll
        for (int n = 0; n < 4; ++n) acc[m][n] = (f32x4)0.f;

    for (int k0 = 0; k0 < 1024; k0 += 32) {
        __syncthreads();
        {
            const float* ap = A + (size_t)(bm * 128 + ar) * 1024 + k0 + ac;
#pragma unroll
            for (int h = 0; h < 2; ++h) {
                float4 v0 = *(const float4*)(ap + h * 8);
                float4 v1 = *(const float4*)(ap + h * 8 + 4);
                float f[8] = {v0.x, v0.y, v0.z, v0.w, v1.x, v1.y, v1.z, v1.w};
                bf16x8 vh, vl;
#pragma unroll
                for (int e = 0; e < 8; ++e) {
                    __bf16 hi = (__bf16)f[e];
                    vh[e] = hi;
                    vl[e] = (__bf16)(f[e] - (float)hi);
                }
                *(bf16x8*)&Ah[ar][ac + h * 8] = vh;
                *(bf16x8*)&Al[ar][ac + h * 8] = vl;
            }
        }
        {
            const float* bp = B + (size_t)(k0 + br) * 1024 + bn * 128 + bc;
#pragma unroll
            for (int q = 0; q < 4; ++q) {
                float4 v = *(const float4*)(bp + q * 4);
                float f[4] = {v.x, v.y, v.z, v.w};
#pragma unroll
                for (int e = 0; e < 4; ++e) {
                    __bf16 hi = (__bf16)f[e];
                    Bh[bc + q * 4 + e][br] = hi;
                    Bl[bc + q * 4 + e][br] = (__bf16)(f[e] - (float)hi);
                }
            }
        }
        __syncthreads();

        bf16x8 fah[4], fal[4], fbh[4], fbl[4];
#pragma unroll
        for (int m = 0; m < 4; ++m) {
            fah[m] = *(const bf16x8*)&Ah[wr * 64 + m * 16 + li][g * 8];
            fal[m] = *(const bf16x8*)&Al[wr * 64 + m * 16 + li][g * 8];
        }
#pragma unroll
        for (int n = 0; n < 4; ++n) {
            fbh[n] = *(const bf16x8*)&Bh[wc * 64 + n * 16 + li][g * 8];
            fbl[n] = *(const bf16x8*)&Bl[wc * 64 + n * 16 + li][g * 8];
        }
#pragma unroll
        for (int m = 0; m < 4; ++m)
#pragma unroll
            for (int n = 0; n < 4; ++n) {
                acc[m][n] = __builtin_amdgcn_mfma_f32_16x16x32_bf16(fah[m], fbh[n], acc[m][n], 0, 0, 0);
                acc[m][n] = __builtin_amdgcn_mfma_f32_16x16x32_bf16(fah[m], fbl[n], acc[m][n], 0, 0, 0);
                acc[m][n] = __builtin_amdgcn_mfma_f32_16x16x32_bf16(fal[m], fbh[n], acc[m][n], 0, 0, 0);
            }
    }

#pragma unroll
    for (int m = 0; m < 4; ++m)
#pragma unroll
        for (int n = 0; n < 4; ++n) {
            const int col = bn * 128 + wc * 64 + n * 16 + li;
            const float bb = bias[col];
#pragma unroll
            for (int e = 0; e < 4; ++e) {
                const int row = bm * 128 + wr * 64 + m * 16 + g * 4 + e;
                C[(size_t)row * 1024 + col] = acc[m][n][e] + bb;
            }
        }
}

// ---------------------------------------------------------------------------
// PROBE: MFMA flash attention (split-bf16 QK^T and PV). Grid (Nq/64, H),
// 256 thr = 4 waves; wave w owns q-row strip [w*16, w*16+16).
// LDS: Q hi/lo [64][72], K hi/lo [64][72] (overlaid with P after QK^T),
// V transposed hi/lo [d][key]. 6 arrays * 9216B = 55.3 KB (< 64 KB).
// Writes dead buffer; check_kernel compares vs fp32 attn (timing side-channel).
// ---------------------------------------------------------------------------
__global__ __launch_bounds__(256) void attn_mfma_kernel(
    const float* __restrict__ Q, const float* __restrict__ Kp,
    const float* __restrict__ Vp, float* __restrict__ ctx, int Nv)
{
    constexpr int PT = 72;   // row pitch (bf16): 144B, 16B-aligned, 2-way banks
    __shared__ alignas(16) __bf16 Qh[64][PT],  Ql[64][PT];
    __shared__ alignas(16) __bf16 KPh[64][PT], KPl[64][PT];  // K tile, then P
    __shared__ alignas(16) __bf16 Vth[64][PT], Vtl[64][PT];  // V^T [d][key]

    const int tid = threadIdx.x;
    const int h  = blockIdx.y;
    const int q0 = blockIdx.x * 64;
    const int wave = tid >> 6, lane = tid & 63;
    const int wr16 = wave * 16;
    const int li = lane & 15, g = lane >> 4;

    // ---- stage Q (pre-scaled 1/sqrt(DH)=0.125, hi/lo split) ----
    {
        const int r = tid >> 2, c0 = (tid & 3) << 4;
        const float* qp = Q + (size_t)(q0 + r) * D + h * DH + c0;
#pragma unroll
        for (int j = 0; j < 2; ++j) {
            float4 v0 = *(const float4*)(qp + j * 8);
            float4 v1 = *(const float4*)(qp + j * 8 + 4);
            float f[8] = {v0.x, v0.y, v0.z, v0.w, v1.x, v1.y, v1.z, v1.w};
            bf16x8 vh, vl;
#pragma unroll
            for (int e = 0; e < 8; ++e) {
                float s = f[e] * 0.125f;
                __bf16 hi = (__bf16)s;
                vh[e] = hi;
                vl[e] = (__bf16)(s - (float)hi);
            }
            *(bf16x8*)&Qh[r][c0 + j * 8] = vh;
            *(bf16x8*)&Ql[r][c0 + j * 8] = vl;
        }
    }

    float m_[4], l_[4];
    f32x4 o_acc[4];
#pragma unroll
    for (int e = 0; e < 4; ++e) { m_[e] = -1e30f; l_[e] = 0.f; }
#pragma unroll
    for (int n = 0; n < 4; ++n) o_acc[n] = (f32x4)0.f;

    for (int kt = 0; kt < Nv; kt += 64) {
        __syncthreads();   // prior PV reads done before K/V overwrite
        // ---- stage K hi/lo ----
        {
            const int r = tid >> 2, c0 = (tid & 3) << 4;
            const float* kp = Kp + (size_t)(kt + r) * D + h * DH + c0;
#pragma unroll
            for (int j = 0; j < 2; ++j) {
                float4 v0 = *(const float4*)(kp + j * 8);
                float4 v1 = *(const float4*)(kp + j * 8 + 4);
                float f[8] = {v0.x, v0.y, v0.z, v0.w, v1.x, v1.y, v1.z, v1.w};
                bf16x8 vh, vl;
#pragma unroll
                for (int e = 0; e < 8; ++e) {
                    __bf16 hi = (__bf16)f[e];
                    vh[e] = hi;
                    vl[e] = (__bf16)(f[e] - (float)hi);
                }
                *(bf16x8*)&KPh[r][c0 + j * 8] = vh;
                *(bf16x8*)&KPl[r][c0 + j * 8] = vl;
            }
        }
        // ---- stage V transposed hi/lo: Vt[d][key] ----
        {
            const int r = tid >> 2, c0 = (tid & 3) << 4;
            const float* vp = Vp + (size_t)(kt + r) * D + h * DH + c0;
#pragma unroll
            for (int j = 0; j < 4; ++j) {
                float4 v = *(const float4*)(vp + j * 4);
                float f[4] = {v.x, v.y, v.z, v.w};
#pragma unroll
                for (int e = 0; e < 4; ++e) {
                    __bf16 hi = (__bf16)f[e];
                    Vth[c0 + j * 4 + e][r] = hi;
                    Vtl[c0 + j * 4 + e][r] = (__bf16)(f[e] - (float)hi);
                }
            }
        }
        __syncthreads();

        // ---- QK^T: S strip [16 q][64 keys], split-bf16 (hh+hl+lh) ----
        bf16x8 qah[2], qal[2];
#pragma unroll
        for (int kk = 0; kk < 2; ++kk) {
            qah[kk] = *(const bf16x8*)&Qh[wr16 + li][kk * 32 + g * 8];
            qal[kk] = *(const bf16x8*)&Ql[wr16 + li][kk * 32 + g * 8];
        }
        f32x4 s_acc[4];
#pragma unroll
        for (int n = 0; n < 4; ++n) s_acc[n] = (f32x4)0.f;
#pragma unroll
        for (int n = 0; n < 4; ++n)
#pragma unroll
            for (int kk = 0; kk < 2; ++kk) {
                bf16x8 kh = *(const bf16x8*)&KPh[n * 16 + li][kk * 32 + g * 8];
                bf16x8 kl = *(const bf16x8*)&KPl[n * 16 + li][kk * 32 + g * 8];
                s_acc[n] = __builtin_amdgcn_mfma_f32_16x16x32_bf16(qah[kk], kh, s_acc[n], 0, 0, 0);
                s_acc[n] = __builtin_amdgcn_mfma_f32_16x16x32_bf16(qah[kk], kl, s_acc[n], 0, 0, 0);
                s_acc[n] = __builtin_amdgcn_mfma_f32_16x16x32_bf16(qal[kk], kh, s_acc[n], 0, 0, 0);
            }

        // ---- online softmax: lane owns rows wr16+g*4+e, cols n*16+li ----
        float rm[4];
#pragma unroll
        for (int e = 0; e < 4; ++e)
            rm[e] = fmaxf(fmaxf(s_acc[0][e], s_acc[1][e]),
                          fmaxf(s_acc[2][e], s_acc[3][e]));
#pragma unroll
        for (int off = 1; off < 16; off <<= 1)
#pragma unroll
            for (int e = 0; e < 4; ++e)
                rm[e] = fmaxf(rm[e], __shfl_xor(rm[e], off, 64));

        float resc[4], rs[4];
#pragma unroll
        for (int e = 0; e < 4; ++e) {
            float mn = fmaxf(m_[e], rm[e]);
            resc[e] = __expf(m_[e] - mn);
            m_[e] = mn;
        }
        float p[4][4];
#pragma unroll
        for (int n = 0; n < 4; ++n)
#pragma unroll
            for (int e = 0; e < 4; ++e)
                p[n][e] = __expf(s_acc[n][e] - m_[e]);
#pragma unroll
        for (int e = 0; e < 4; ++e)
            rs[e] = p[0][e] + p[1][e] + p[2][e] + p[3][e];
#pragma unroll
        for (int off = 1; off < 16; off <<= 1)
#pragma unroll
            for (int e = 0; e < 4; ++e)
                rs[e] += __shfl_xor(rs[e], off, 64);
#pragma unroll
        for (int e = 0; e < 4; ++e)
            l_[e] = l_[e] * resc[e] + rs[e];
#pragma unroll
        for (int n = 0; n < 4; ++n)
#pragma unroll
            for (int e = 0; e < 4; ++e)
                o_acc[n][e] *= resc[e];

        __syncthreads();   // all waves done reading K before P overlays it

        // ---- write P hi/lo into K's LDS space ----
#pragma unroll
        for (int n = 0; n < 4; ++n)
#pragma unroll
            for (int e = 0; e < 4; ++e) {
                const int row = wr16 + g * 4 + e;
                const int col = n * 16 + li;
                float pv = p[n][e];
                __bf16 hi = (__bf16)pv;
                KPh[row][col] = hi;
                KPl[row][col] = (__bf16)(pv - (float)hi);
            }
        __syncthreads();

        // ---- PV: O strip [16 q][64 d] += P @ V ----
        bf16x8 pah[2], pal[2];
#pragma unroll
        for (int kk = 0; kk < 2; ++kk) {
            pah[kk] = *(const bf16x8*)&KPh[wr16 + li][kk * 32 + g * 8];
            pal[kk] = *(const bf16x8*)&KPl[wr16 + li][kk * 32 + g * 8];
        }
#pragma unroll
        for (int n = 0; n < 4; ++n)
#pragma unroll
            for (int kk = 0; kk < 2; ++kk) {
                bf16x8 vh = *(const bf16x8*)&Vth[n * 16 + li][kk * 32 + g * 8];
                bf16x8 vl = *(const bf16x8*)&Vtl[n * 16 + li][kk * 32 + g * 8];
                o_acc[n] = __builtin_amdgcn_mfma_f32_16x16x32_bf16(pah[kk], vh, o_acc[n], 0, 0, 0);
                o_acc[n] = __builtin_amdgcn_mfma_f32_16x16x32_bf16(pah[kk], vl, o_acc[n], 0, 0, 0);
                o_acc[n] = __builtin_amdgcn_mfma_f32_16x16x32_bf16(pal[kk], vh, o_acc[n], 0, 0, 0);
            }
    }

    // ---- epilogue ----
    float inv[4];
#pragma unroll
    for (int e = 0; e < 4; ++e) inv[e] = 1.f / l_[e];
#pragma unroll
    for (int n = 0; n < 4; ++n)
#pragma unroll
        for (int e = 0; e < 4; ++e) {
            const int row = q0 + wr16 + g * 4 + e;
            const int col = h * DH + n * 16 + li;
            ctx[(size_t)row * D + col] = o_acc[n][e] * inv[e];
        }
}

// ---------------------------------------------------------------------------
// Checker w/ timing side-channel: mismatch > tol -> ~3ms dependent-FMA chain.
// ---------------------------------------------------------------------------
__global__ __launch_bounds__(256) void check_kernel(
    const float* __restrict__ X, const float* __restrict__ Y, float* flag, float tol)
{
    const size_t i = ((size_t)blockIdx.x * 256 + threadIdx.x) * 4;
    float4 x = *(const float4*)&X[i];
    float4 y = *(const float4*)&Y[i];
    float d = fmaxf(fmaxf(fabsf(x.x - y.x), fabsf(x.y - y.y)),
                    fmaxf(fabsf(x.z - y.z), fabsf(x.w - y.w)));
    if (d > tol) {
        float z = d;
        for (int it = 0; it < 2000000; ++it) z = fmaf(z, 1.0000001f, 1e-7f);
        if (z == 123.456f) atomicAdd(flag, 1.f);
    }
}

// ---------------------------------------------------------------------------
// fp32 flash attention (verified; real path this round).
// ---------------------------------------------------------------------------
__global__ __launch_bounds__(256) void attn_kernel(
    const float* __restrict__ Q, const float* __restrict__ Kp,
    const float* __restrict__ Vp, float* __restrict__ ctx, int Nv)
{
    __shared__ float Qs[DH][68];
    __shared__ float Ks[DH][68];
    __shared__ float Vs[64][68];
    __shared__ float Ps[64][68];

    const int tid = threadIdx.x;
    const int h  = blockIdx.y;
    const int q0 = blockIdx.x * 64;
    const int tr = tid >> 4;
    const int tc = tid & 15;

#pragma unroll
    for (int it = 0; it < 4; ++it) {
        int idx = tid + 256 * it;
        int row = idx >> 4;
        int d4  = (idx & 15) << 2;
        float4 v = *(const float4*)&Q[(size_t)(q0 + row) * D + h * DH + d4];
        Qs[d4 + 0][row] = v.x * 0.125f;
        Qs[d4 + 1][row] = v.y * 0.125f;
        Qs[d4 + 2][row] = v.z * 0.125f;
        Qs[d4 + 3][row] = v.w * 0.125f;
    }

    float m[4], l[4], O[4][4];
#pragma unroll
    for (int i = 0; i < 4; ++i) {
        m[i] = -1e30f; l[i] = 0.f;
#pragma unroll
        for (int j = 0; j < 4; ++j) O[i][j] = 0.f;
    }

    for (int kt = 0; kt < Nv; kt += 64) {
        __syncthreads();
#pragma unroll
        for (int it = 0; it < 4; ++it) {
            int idx = tid + 256 * it;
            int row = idx >> 4;
            int d4  = (idx & 15) << 2;
            float4 kv = *(const float4*)&Kp[(size_t)(kt + row) * D + h * DH + d4];
            Ks[d4 + 0][row] = kv.x;
            Ks[d4 + 1][row] = kv.y;
            Ks[d4 + 2][row] = kv.z;
            Ks[d4 + 3][row] = kv.w;
            float4 vv = *(const float4*)&Vp[(size_t)(kt + row) * D + h * DH + d4];
            *(float4*)&Vs[row][d4] = vv;
        }
        __syncthreads();

        float s[4][4];
#pragma unroll
        for (int i = 0; i < 4; ++i)
#pragma unroll
            for (int j = 0; j < 4; ++j) s[i][j] = 0.f;

        for (int d = 0; d < DH; ++d) {
            float4 qv = *(const float4*)&Qs[d][tr * 4];
            float4 kv = *(const float4*)&Ks[d][tc * 4];
            float qa[4] = {qv.x, qv.y, qv.z, qv.w};
            float ka[4] = {kv.x, kv.y, kv.z, kv.w};
#pragma unroll
            for (int i = 0; i < 4; ++i)
#pragma unroll
                for (int j = 0; j < 4; ++j)
                    s[i][j] = fmaf(qa[i], ka[j], s[i][j]);
        }

        float rm[4];
#pragma unroll
        for (int i = 0; i < 4; ++i)
            rm[i] = fmaxf(fmaxf(s[i][0], s[i][1]), fmaxf(s[i][2], s[i][3]));
#pragma unroll
        for (int off = 1; off < 16; off <<= 1)
#pragma unroll
            for (int i = 0; i < 4; ++i)
                rm[i] = fmaxf(rm[i], __shfl_xor(rm[i], off, 64));

        float al[4], rs[4];
#pragma unroll
        for (int i = 0; i < 4; ++i) {
            float mn = fmaxf(m[i], rm[i]);
            al[i] = __expf(m[i] - mn);
            m[i] = mn;
            float acc = 0.f;
#pragma unroll
            for (int j = 0; j < 4; ++j) {
                s[i][j] = __expf(s[i][j] - mn);
                acc += s[i][j];
            }
            rs[i] = acc;
        }
#pragma unroll
        for (int off = 1; off < 16; off <<= 1)
#pragma unroll
            for (int i = 0; i < 4; ++i)
                rs[i] += __shfl_xor(rs[i], off, 64);
#pragma unroll
        for (int i = 0; i < 4; ++i) {
            l[i] = l[i] * al[i] + rs[i];
#pragma unroll
            for (int j = 0; j < 4; ++j) O[i][j] *= al[i];
        }

#pragma unroll
        for (int i = 0; i < 4; ++i)
#pragma unroll
            for (int j = 0; j < 4; ++j)
                Ps[tc * 4 + j][tr * 4 + i] = s[i][j];
        __syncthreads();

        for (int k = 0; k < 64; ++k) {
            float4 pv = *(const float4*)&Ps[k][tr * 4];
            float4 vv = *(const float4*)&Vs[k][tc * 4];
            float pa[4] = {pv.x, pv.y, pv.z, pv.w};
            float va[4] = {vv.x, vv.y, vv.z, vv.w};
#pragma unroll
            for (int i = 0; i < 4; ++i)
#pragma unroll
                for (int j = 0; j < 4; ++j)
                    O[i][j] = fmaf(pa[i], va[j], O[i][j]);
        }
    }

#pragma unroll
    for (int i = 0; i < 4; ++i) {
        const int row = q0 + tr * 4 + i;
        const float inv = 1.f / l[i];
        float4 o;
        o.x = O[i][0] * inv; o.y = O[i][1] * inv;
        o.z = O[i][2] * inv; o.w = O[i][3] * inv;
        *(float4*)&ctx[(size_t)row * D + h * DH + tc * 4] = o;
    }
}

// ---------------------------------------------------------------------------
// Fused residual + LN(1e-12) + LN(1e-5). One block per row.
// ---------------------------------------------------------------------------
__global__ __launch_bounds__(256) void resid_dual_ln_kernel(
    const float* __restrict__ att, const float* __restrict__ resid,
    const float* __restrict__ g1, const float* __restrict__ b1,
    const float* __restrict__ g2, const float* __restrict__ b2,
    float* __restrict__ out)
{
    const int row = blockIdx.x;
    const int tid = threadIdx.x;
    const int c = tid << 2;
    const size_t base = (size_t)row * D + c;

    float4 a = *(const float4*)&att[base];
    float4 r = *(const float4*)&resid[base];
    float t[4] = {a.x + r.x, a.y + r.y, a.z + r.z, a.w + r.w};

    __shared__ float red[8];
    const int wid = tid >> 6, lane = tid & 63;

    float s = t[0] + t[1] + t[2] + t[3];
    float sq = t[0]*t[0] + t[1]*t[1] + t[2]*t[2] + t[3]*t[3];
#pragma unroll
    for (int off = 1; off < 64; off <<= 1) {
        s  += __shfl_xor(s, off, 64);
        sq += __shfl_xor(sq, off, 64);
    }
    if (lane == 0) { red[wid] = s; red[4 + wid] = sq; }
    __syncthreads();
    s  = red[0] + red[1] + red[2] + red[3];
    sq = red[4] + red[5] + red[6] + red[7];

    float mu  = s * (1.f / D);
    float var = sq * (1.f / D) - mu * mu;
    float rr  = rsqrtf(var + 1e-12f);

    float4 G1 = *(const float4*)&g1[c];
    float4 B1 = *(const float4*)&b1[c];
    float g1a[4] = {G1.x, G1.y, G1.z, G1.w};
    float b1a[4] = {B1.x, B1.y, B1.z, B1.w};
    float v[4];
#pragma unroll
    for (int j = 0; j < 4; ++j) v[j] = (t[j] - mu) * rr * g1a[j] + b1a[j];

    float s2 = v[0] + v[1] + v[2] + v[3];
    float q2 = v[0]*v[0] + v[1]*v[1] + v[2]*v[2] + v[3]*v[3];
#pragma unroll
    for (int off = 1; off < 64; off <<= 1) {
        s2 += __shfl_xor(s2, off, 64);
        q2 += __shfl_xor(q2, off, 64);
    }
    __syncthreads();
    if (lane == 0) { red[wid] = s2; red[4 + wid] = q2; }
    __syncthreads();
    s2 = red[0] + red[1] + red[2] + red[3];
    q2 = red[4] + red[5] + red[6] + red[7];

    float mu2  = s2 * (1.f / D);
    float var2 = q2 * (1.f / D) - mu2 * mu2;
    float r2   = rsqrtf(var2 + 1e-5f);

    float4 G2 = *(const float4*)&g2[c];
    float4 B2 = *(const float4*)&b2[c];
    float g2a[4] = {G2.x, G2.y, G2.z, G2.w};
    float b2a[4] = {B2.x, B2.y, B2.z, B2.w};
    float4 o;
    float oo[4];
#pragma unroll
    for (int j = 0; j < 4; ++j) oo[j] = (v[j] - mu2) * r2 * g2a[j] + b2a[j];
    o.x = oo[0]; o.y = oo[1]; o.z = oo[2]; o.w = oo[3];
    *(float4*)&out[base] = o;
}

// ---------------------------------------------------------------------------
// ws (floats): Qp[Nq*D] | Kp[Nv*D] | Vp[Nv*D] | ctx[Nq*D] | ctx2[Nq*D] | flag
// aliases: att = Qp (Q dead after both attns); x2 = ctx2 (dead after check).
// ---------------------------------------------------------------------------
extern "C" void kernel_launch(void* const* d_in, const int* in_sizes, int n_in,
                              void* d_out, int out_size, void* d_ws, size_t ws_size,
                              hipStream_t stream)
{
    const float* qf  = (const float*)d_in[0];
    const float* vf  = (const float*)d_in[1];
    const float* Wq  = (const float*)d_in[2];
    const float* bq  = (const float*)d_in[3];
    const float* Wk  = (const float*)d_in[4];
    const float* bk  = (const float*)d_in[5];
    const float* Wv  = (const float*)d_in[6];
    const float* bv  = (const float*)d_in[7];
    const float* Wo  = (const float*)d_in[8];
    const float* bo  = (const float*)d_in[9];
    const float* g1  = (const float*)d_in[10];
    const float* b1  = (const float*)d_in[11];
    const float* g2  = (const float*)d_in[12];
    const float* b2  = (const float*)d_in[13];
    const float* Wl  = (const float*)d_in[14];
    const float* bl  = (const float*)d_in[15];

    const int Nq = in_sizes[0] / D;   // 4096
    const int Nv = in_sizes[1] / D;   // 1024

    float* ws   = (float*)d_ws;
    float* Qp   = ws;
    float* Kp   = Qp  + (size_t)Nq * D;
    float* Vp   = Kp  + (size_t)Nv * D;
    float* ctx  = Vp  + (size_t)Nv * D;
    float* ctx2 = ctx + (size_t)Nq * D;
    float* flag = ctx2 + (size_t)Nq * D;
    float* att  = Qp;
    float* x2   = ctx2;

    const size_t need = ((size_t)(3 * Nq + 2 * Nv) * D + 16) * sizeof(float);
    const bool do_probe = (ws_size >= need);

    dim3 blk(256);
    mfma_gemm_bias<<<dim3(8, Nq / 128), blk, 0, stream>>>(qf, Wq, bq, Qp);
    mfma_gemm_bias<<<dim3(8, Nv / 128), blk, 0, stream>>>(vf, Wk, bk, Kp);
    mfma_gemm_bias<<<dim3(8, Nv / 128), blk, 0, stream>>>(vf, Wv, bv, Vp);
    attn_kernel<<<dim3(Nq / 64, NH), blk, 0, stream>>>(Qp, Kp, Vp, ctx, Nv);
    if (do_probe) {
        attn_mfma_kernel<<<dim3(Nq / 64, NH), blk, 0, stream>>>(Qp, Kp, Vp, ctx2, Nv);
        check_kernel<<<dim3((Nq * D) / 1024), blk, 0, stream>>>(ctx2, ctx, flag, 5e-3f);
    }
    mfma_gemm_bias<<<dim3(8, Nq / 128), blk, 0, stream>>>(ctx, Wo, bo, att);
    resid_dual_ln_kernel<<<dim3(Nq), blk, 0, stream>>>(att, qf, g1, b1, g2, b2, x2);
    mfma_gemm_bias<<<dim3(8, Nq / 128), blk, 0, stream>>>(x2, Wl, bl, (float*)d_out);
}

// Round 5
// 678.820 us; speedup vs baseline: 1.5547x; 1.3360x over previous
//
#include <hip/hip_runtime.h>

static constexpr int D  = 1024;
static constexpr int NH = 16;
static constexpr int DH = 64;

using bf16x8 = __attribute__((ext_vector_type(8))) __bf16;
using bf16x4 = __attribute__((ext_vector_type(4))) __bf16;
using f32x4  = __attribute__((ext_vector_type(4))) float;

// ---------------------------------------------------------------------------
// Split-bf16 MFMA GEMM (HW-verified r3): C = A@B + bias, fp32 in/out.
// 3 MFMA products (hh, hl, lh), fp32 accum. Tile 128x128, BK=32, 4 waves.
// ---------------------------------------------------------------------------
__global__ __launch_bounds__(256) void mfma_gemm_bias(
    const float* __restrict__ A, const float* __restrict__ B,
    const float* __restrict__ bias, float* __restrict__ C)
{
    __shared__ alignas(16) __bf16 Ah[128][40], Al[128][40];
    __shared__ alignas(16) __bf16 Bh[128][40], Bl[128][40];   // [n-col][k]

    const int tid = threadIdx.x;
    const int bm = blockIdx.y, bn = blockIdx.x;
    const int wave = tid >> 6, lane = tid & 63;
    const int wr = wave >> 1, wc = wave & 1;
    const int li = lane & 15, g = lane >> 4;

    const int ar = tid >> 1, ac = (tid & 1) << 4;
    const int br = tid >> 3, bc = (tid & 7) << 4;

    f32x4 acc[4][4];
#pragma unroll
    for (int m = 0; m < 4; ++m)
#pragma unroll
        for (int n = 0; n < 4; ++n) acc[m][n] = (f32x4)0.f;

    for (int k0 = 0; k0 < 1024; k0 += 32) {
        __syncthreads();
        {
            const float* ap = A + (size_t)(bm * 128 + ar) * 1024 + k0 + ac;
#pragma unroll
            for (int h = 0; h < 2; ++h) {
                float4 v0 = *(const float4*)(ap + h * 8);
                float4 v1 = *(const float4*)(ap + h * 8 + 4);
                float f[8] = {v0.x, v0.y, v0.z, v0.w, v1.x, v1.y, v1.z, v1.w};
                bf16x8 vh, vl;
#pragma unroll
                for (int e = 0; e < 8; ++e) {
                    __bf16 hi = (__bf16)f[e];
                    vh[e] = hi;
                    vl[e] = (__bf16)(f[e] - (float)hi);
                }
                *(bf16x8*)&Ah[ar][ac + h * 8] = vh;
                *(bf16x8*)&Al[ar][ac + h * 8] = vl;
            }
        }
        {
            const float* bp = B + (size_t)(k0 + br) * 1024 + bn * 128 + bc;
#pragma unroll
            for (int q = 0; q < 4; ++q) {
                float4 v = *(const float4*)(bp + q * 4);
                float f[4] = {v.x, v.y, v.z, v.w};
#pragma unroll
                for (int e = 0; e < 4; ++e) {
                    __bf16 hi = (__bf16)f[e];
                    Bh[bc + q * 4 + e][br] = hi;
                    Bl[bc + q * 4 + e][br] = (__bf16)(f[e] - (float)hi);
                }
            }
        }
        __syncthreads();

        bf16x8 fah[4], fal[4], fbh[4], fbl[4];
#pragma unroll
        for (int m = 0; m < 4; ++m) {
            fah[m] = *(const bf16x8*)&Ah[wr * 64 + m * 16 + li][g * 8];
            fal[m] = *(const bf16x8*)&Al[wr * 64 + m * 16 + li][g * 8];
        }
#pragma unroll
        for (int n = 0; n < 4; ++n) {
            fbh[n] = *(const bf16x8*)&Bh[wc * 64 + n * 16 + li][g * 8];
            fbl[n] = *(const bf16x8*)&Bl[wc * 64 + n * 16 + li][g * 8];
        }
#pragma unroll
        for (int m = 0; m < 4; ++m)
#pragma unroll
            for (int n = 0; n < 4; ++n) {
                acc[m][n] = __builtin_amdgcn_mfma_f32_16x16x32_bf16(fah[m], fbh[n], acc[m][n], 0, 0, 0);
                acc[m][n] = __builtin_amdgcn_mfma_f32_16x16x32_bf16(fah[m], fbl[n], acc[m][n], 0, 0, 0);
                acc[m][n] = __builtin_amdgcn_mfma_f32_16x16x32_bf16(fal[m], fbh[n], acc[m][n], 0, 0, 0);
            }
    }

#pragma unroll
    for (int m = 0; m < 4; ++m)
#pragma unroll
        for (int n = 0; n < 4; ++n) {
            const int col = bn * 128 + wc * 64 + n * 16 + li;
            const float bb = bias[col];
#pragma unroll
            for (int e = 0; e < 4; ++e) {
                const int row = bm * 128 + wr * 64 + m * 16 + g * 4 + e;
                C[(size_t)row * 1024 + col] = acc[m][n][e] + bb;
            }
        }
}

// ---------------------------------------------------------------------------
// Weight pre-split+transpose: W[k][n] fp32 -> Th[n][k], Tl[n][k] bf16 hi/lo.
// Grid (32,32), 256 thr, 32x32 LDS tile.
// ---------------------------------------------------------------------------
__global__ __launch_bounds__(256) void split_transpose_w(
    const float* __restrict__ W, __bf16* __restrict__ Th, __bf16* __restrict__ Tl)
{
    __shared__ float tile[32][33];
    const int t = threadIdx.x;
    const int r = t >> 3;           // 0..31
    const int c4 = (t & 7) << 2;    // 0..28
    const int n0 = blockIdx.x * 32, k0 = blockIdx.y * 32;

    float4 v = *(const float4*)&W[(size_t)(k0 + r) * 1024 + n0 + c4];
    tile[r][c4 + 0] = v.x; tile[r][c4 + 1] = v.y;
    tile[r][c4 + 2] = v.z; tile[r][c4 + 3] = v.w;
    __syncthreads();

    float f[4] = {tile[c4 + 0][r], tile[c4 + 1][r], tile[c4 + 2][r], tile[c4 + 3][r]};
    bf16x4 vh, vl;
#pragma unroll
    for (int e = 0; e < 4; ++e) {
        __bf16 hi = (__bf16)f[e];
        vh[e] = hi;
        vl[e] = (__bf16)(f[e] - (float)hi);
    }
    const size_t o = (size_t)(n0 + r) * 1024 + k0 + c4;
    *(bf16x4*)&Th[o] = vh;
    *(bf16x4*)&Tl[o] = vl;
}

// ---------------------------------------------------------------------------
// PROBE GEMM v2: A fp32 (split in-kernel, same as verified), B pre-split
// pre-transposed bf16 (vectorized copy staging). Same fragments/MFMA/epilogue.
// ---------------------------------------------------------------------------
__global__ __launch_bounds__(256) void mfma_gemm_v2(
    const float* __restrict__ A, const __bf16* __restrict__ BTh,
    const __bf16* __restrict__ BTl, const float* __restrict__ bias,
    float* __restrict__ C)
{
    __shared__ alignas(16) __bf16 Ah[128][40], Al[128][40];
    __shared__ alignas(16) __bf16 Bh[128][40], Bl[128][40];

    const int tid = threadIdx.x;
    const int bm = blockIdx.y, bn = blockIdx.x;
    const int wave = tid >> 6, lane = tid & 63;
    const int wr = wave >> 1, wc = wave & 1;
    const int li = lane & 15, g = lane >> 4;

    const int ar = tid >> 1, ac = (tid & 1) << 4;
    const int nb = tid >> 1, kh = (tid & 1) << 4;   // B: 2 thr/row, 16 k each

    f32x4 acc[4][4];
#pragma unroll
    for (int m = 0; m < 4; ++m)
#pragma unroll
        for (int n = 0; n < 4; ++n) acc[m][n] = (f32x4)0.f;

    for (int k0 = 0; k0 < 1024; k0 += 32) {
        __syncthreads();
        {
            const float* ap = A + (size_t)(bm * 128 + ar) * 1024 + k0 + ac;
#pragma unroll
            for (int h = 0; h < 2; ++h) {
                float4 v0 = *(const float4*)(ap + h * 8);
                float4 v1 = *(const float4*)(ap + h * 8 + 4);
                float f[8] = {v0.x, v0.y, v0.z, v0.w, v1.x, v1.y, v1.z, v1.w};
                bf16x8 vh, vl;
#pragma unroll
                for (int e = 0; e < 8; ++e) {
                    __bf16 hi = (__bf16)f[e];
                    vh[e] = hi;
                    vl[e] = (__bf16)(f[e] - (float)hi);
                }
                *(bf16x8*)&Ah[ar][ac + h * 8] = vh;
                *(bf16x8*)&Al[ar][ac + h * 8] = vl;
            }
        }
        {
            const size_t o = (size_t)(bn * 128 + nb) * 1024 + k0 + kh;
            *(bf16x8*)&Bh[nb][kh]     = *(const bf16x8*)(BTh + o);
            *(bf16x8*)&Bh[nb][kh + 8] = *(const bf16x8*)(BTh + o + 8);
            *(bf16x8*)&Bl[nb][kh]     = *(const bf16x8*)(BTl + o);
            *(bf16x8*)&Bl[nb][kh + 8] = *(const bf16x8*)(BTl + o + 8);
        }
        __syncthreads();

        bf16x8 fah[4], fal[4], fbh[4], fbl[4];
#pragma unroll
        for (int m = 0; m < 4; ++m) {
            fah[m] = *(const bf16x8*)&Ah[wr * 64 + m * 16 + li][g * 8];
            fal[m] = *(const bf16x8*)&Al[wr * 64 + m * 16 + li][g * 8];
        }
#pragma unroll
        for (int n = 0; n < 4; ++n) {
            fbh[n] = *(const bf16x8*)&Bh[wc * 64 + n * 16 + li][g * 8];
            fbl[n] = *(const bf16x8*)&Bl[wc * 64 + n * 16 + li][g * 8];
        }
#pragma unroll
        for (int m = 0; m < 4; ++m)
#pragma unroll
            for (int n = 0; n < 4; ++n) {
                acc[m][n] = __builtin_amdgcn_mfma_f32_16x16x32_bf16(fah[m], fbh[n], acc[m][n], 0, 0, 0);
                acc[m][n] = __builtin_amdgcn_mfma_f32_16x16x32_bf16(fah[m], fbl[n], acc[m][n], 0, 0, 0);
                acc[m][n] = __builtin_amdgcn_mfma_f32_16x16x32_bf16(fal[m], fbh[n], acc[m][n], 0, 0, 0);
            }
    }

#pragma unroll
    for (int m = 0; m < 4; ++m)
#pragma unroll
        for (int n = 0; n < 4; ++n) {
            const int col = bn * 128 + wc * 64 + n * 16 + li;
            const float bb = bias[col];
#pragma unroll
            for (int e = 0; e < 4; ++e) {
                const int row = bm * 128 + wr * 64 + m * 16 + g * 4 + e;
                C[(size_t)row * 1024 + col] = acc[m][n][e] + bb;
            }
        }
}

// ---------------------------------------------------------------------------
// Checker w/ timing side-channel: mismatch > tol -> ~3ms dependent-FMA chain.
// ---------------------------------------------------------------------------
__global__ __launch_bounds__(256) void check_kernel(
    const float* __restrict__ X, const float* __restrict__ Y, float* flag, float tol)
{
    const size_t i = ((size_t)blockIdx.x * 256 + threadIdx.x) * 4;
    float4 x = *(const float4*)&X[i];
    float4 y = *(const float4*)&Y[i];
    float d = fmaxf(fmaxf(fabsf(x.x - y.x), fabsf(x.y - y.y)),
                    fmaxf(fabsf(x.z - y.z), fabsf(x.w - y.w)));
    if (d > tol) {
        float z = d;
        for (int it = 0; it < 2000000; ++it) z = fmaf(z, 1.0000001f, 1e-7f);
        if (z == 123.456f) atomicAdd(flag, 1.f);
    }
}

// ---------------------------------------------------------------------------
// MFMA flash attention (HW-verified r4, now the real path).
// Grid (Nq/64, H), 4 waves; wave w owns q-strip [w*16, w*16+16).
// ---------------------------------------------------------------------------
__global__ __launch_bounds__(256) void attn_mfma_kernel(
    const float* __restrict__ Q, const float* __restrict__ Kp,
    const float* __restrict__ Vp, float* __restrict__ ctx, int Nv)
{
    constexpr int PT = 72;
    __shared__ alignas(16) __bf16 Qh[64][PT],  Ql[64][PT];
    __shared__ alignas(16) __bf16 KPh[64][PT], KPl[64][PT];
    __shared__ alignas(16) __bf16 Vth[64][PT], Vtl[64][PT];

    const int tid = threadIdx.x;
    const int h  = blockIdx.y;
    const int q0 = blockIdx.x * 64;
    const int wave = tid >> 6, lane = tid & 63;
    const int wr16 = wave * 16;
    const int li = lane & 15, g = lane >> 4;

    {
        const int r = tid >> 2, c0 = (tid & 3) << 4;
        const float* qp = Q + (size_t)(q0 + r) * D + h * DH + c0;
#pragma unroll
        for (int j = 0; j < 2; ++j) {
            float4 v0 = *(const float4*)(qp + j * 8);
            float4 v1 = *(const float4*)(qp + j * 8 + 4);
            float f[8] = {v0.x, v0.y, v0.z, v0.w, v1.x, v1.y, v1.z, v1.w};
            bf16x8 vh, vl;
#pragma unroll
            for (int e = 0; e < 8; ++e) {
                float s = f[e] * 0.125f;
                __bf16 hi = (__bf16)s;
                vh[e] = hi;
                vl[e] = (__bf16)(s - (float)hi);
            }
            *(bf16x8*)&Qh[r][c0 + j * 8] = vh;
            *(bf16x8*)&Ql[r][c0 + j * 8] = vl;
        }
    }

    float m_[4], l_[4];
    f32x4 o_acc[4];
#pragma unroll
    for (int e = 0; e < 4; ++e) { m_[e] = -1e30f; l_[e] = 0.f; }
#pragma unroll
    for (int n = 0; n < 4; ++n) o_acc[n] = (f32x4)0.f;

    for (int kt = 0; kt < Nv; kt += 64) {
        __syncthreads();
        {
            const int r = tid >> 2, c0 = (tid & 3) << 4;
            const float* kp = Kp + (size_t)(kt + r) * D + h * DH + c0;
#pragma unroll
            for (int j = 0; j < 2; ++j) {
                float4 v0 = *(const float4*)(kp + j * 8);
                float4 v1 = *(const float4*)(kp + j * 8 + 4);
                float f[8] = {v0.x, v0.y, v0.z, v0.w, v1.x, v1.y, v1.z, v1.w};
                bf16x8 vh, vl;
#pragma unroll
                for (int e = 0; e < 8; ++e) {
                    __bf16 hi = (__bf16)f[e];
                    vh[e] = hi;
                    vl[e] = (__bf16)(f[e] - (float)hi);
                }
                *(bf16x8*)&KPh[r][c0 + j * 8] = vh;
                *(bf16x8*)&KPl[r][c0 + j * 8] = vl;
            }
        }
        {
            const int r = tid >> 2, c0 = (tid & 3) << 4;
            const float* vp = Vp + (size_t)(kt + r) * D + h * DH + c0;
#pragma unroll
            for (int j = 0; j < 4; ++j) {
                float4 v = *(const float4*)(vp + j * 4);
                float f[4] = {v.x, v.y, v.z, v.w};
#pragma unroll
                for (int e = 0; e < 4; ++e) {
                    __bf16 hi = (__bf16)f[e];
                    Vth[c0 + j * 4 + e][r] = hi;
                    Vtl[c0 + j * 4 + e][r] = (__bf16)(f[e] - (float)hi);
                }
            }
        }
        __syncthreads();

        bf16x8 qah[2], qal[2];
#pragma unroll
        for (int kk = 0; kk < 2; ++kk) {
            qah[kk] = *(const bf16x8*)&Qh[wr16 + li][kk * 32 + g * 8];
            qal[kk] = *(const bf16x8*)&Ql[wr16 + li][kk * 32 + g * 8];
        }
        f32x4 s_acc[4];
#pragma unroll
        for (int n = 0; n < 4; ++n) s_acc[n] = (f32x4)0.f;
#pragma unroll
        for (int n = 0; n < 4; ++n)
#pragma unroll
            for (int kk = 0; kk < 2; ++kk) {
                bf16x8 kh = *(const bf16x8*)&KPh[n * 16 + li][kk * 32 + g * 8];
                bf16x8 kl = *(const bf16x8*)&KPl[n * 16 + li][kk * 32 + g * 8];
                s_acc[n] = __builtin_amdgcn_mfma_f32_16x16x32_bf16(qah[kk], kh, s_acc[n], 0, 0, 0);
                s_acc[n] = __builtin_amdgcn_mfma_f32_16x16x32_bf16(qah[kk], kl, s_acc[n], 0, 0, 0);
                s_acc[n] = __builtin_amdgcn_mfma_f32_16x16x32_bf16(qal[kk], kh, s_acc[n], 0, 0, 0);
            }

        float rm[4];
#pragma unroll
        for (int e = 0; e < 4; ++e)
            rm[e] = fmaxf(fmaxf(s_acc[0][e], s_acc[1][e]),
                          fmaxf(s_acc[2][e], s_acc[3][e]));
#pragma unroll
        for (int off = 1; off < 16; off <<= 1)
#pragma unroll
            for (int e = 0; e < 4; ++e)
                rm[e] = fmaxf(rm[e], __shfl_xor(rm[e], off, 64));

        float resc[4], rs[4];
#pragma unroll
        for (int e = 0; e < 4; ++e) {
            float mn = fmaxf(m_[e], rm[e]);
            resc[e] = __expf(m_[e] - mn);
            m_[e] = mn;
        }
        float p[4][4];
#pragma unroll
        for (int n = 0; n < 4; ++n)
#pragma unroll
            for (int e = 0; e < 4; ++e)
                p[n][e] = __expf(s_acc[n][e] - m_[e]);
#pragma unroll
        for (int e = 0; e < 4; ++e)
            rs[e] = p[0][e] + p[1][e] + p[2][e] + p[3][e];
#pragma unroll
        for (int off = 1; off < 16; off <<= 1)
#pragma unroll
            for (int e = 0; e < 4; ++e)
                rs[e] += __shfl_xor(rs[e], off, 64);
#pragma unroll
        for (int e = 0; e < 4; ++e)
            l_[e] = l_[e] * resc[e] + rs[e];
#pragma unroll
        for (int n = 0; n < 4; ++n)
#pragma unroll
            for (int e = 0; e < 4; ++e)
                o_acc[n][e] *= resc[e];

        __syncthreads();

#pragma unroll
        for (int n = 0; n < 4; ++n)
#pragma unroll
            for (int e = 0; e < 4; ++e) {
                const int row = wr16 + g * 4 + e;
                const int col = n * 16 + li;
                float pv = p[n][e];
                __bf16 hi = (__bf16)pv;
                KPh[row][col] = hi;
                KPl[row][col] = (__bf16)(pv - (float)hi);
            }
        __syncthreads();

        bf16x8 pah[2], pal[2];
#pragma unroll
        for (int kk = 0; kk < 2; ++kk) {
            pah[kk] = *(const bf16x8*)&KPh[wr16 + li][kk * 32 + g * 8];
            pal[kk] = *(const bf16x8*)&KPl[wr16 + li][kk * 32 + g * 8];
        }
#pragma unroll
        for (int n = 0; n < 4; ++n)
#pragma unroll
            for (int kk = 0; kk < 2; ++kk) {
                bf16x8 vh = *(const bf16x8*)&Vth[n * 16 + li][kk * 32 + g * 8];
                bf16x8 vl = *(const bf16x8*)&Vtl[n * 16 + li][kk * 32 + g * 8];
                o_acc[n] = __builtin_amdgcn_mfma_f32_16x16x32_bf16(pah[kk], vh, o_acc[n], 0, 0, 0);
                o_acc[n] = __builtin_amdgcn_mfma_f32_16x16x32_bf16(pah[kk], vl, o_acc[n], 0, 0, 0);
                o_acc[n] = __builtin_amdgcn_mfma_f32_16x16x32_bf16(pal[kk], vh, o_acc[n], 0, 0, 0);
            }
    }

    float inv[4];
#pragma unroll
    for (int e = 0; e < 4; ++e) inv[e] = 1.f / l_[e];
#pragma unroll
    for (int n = 0; n < 4; ++n)
#pragma unroll
        for (int e = 0; e < 4; ++e) {
            const int row = q0 + wr16 + g * 4 + e;
            const int col = h * DH + n * 16 + li;
            ctx[(size_t)row * D + col] = o_acc[n][e] * inv[e];
        }
}

// ---------------------------------------------------------------------------
// Fused residual + LN(1e-12) + LN(1e-5). One block per row.
// ---------------------------------------------------------------------------
__global__ __launch_bounds__(256) void resid_dual_ln_kernel(
    const float* __restrict__ att, const float* __restrict__ resid,
    const float* __restrict__ g1, const float* __restrict__ b1,
    const float* __restrict__ g2, const float* __restrict__ b2,
    float* __restrict__ out)
{
    const int row = blockIdx.x;
    const int tid = threadIdx.x;
    const int c = tid << 2;
    const size_t base = (size_t)row * D + c;

    float4 a = *(const float4*)&att[base];
    float4 r = *(const float4*)&resid[base];
    float t[4] = {a.x + r.x, a.y + r.y, a.z + r.z, a.w + r.w};

    __shared__ float red[8];
    const int wid = tid >> 6, lane = tid & 63;

    float s = t[0] + t[1] + t[2] + t[3];
    float sq = t[0]*t[0] + t[1]*t[1] + t[2]*t[2] + t[3]*t[3];
#pragma unroll
    for (int off = 1; off < 64; off <<= 1) {
        s  += __shfl_xor(s, off, 64);
        sq += __shfl_xor(sq, off, 64);
    }
    if (lane == 0) { red[wid] = s; red[4 + wid] = sq; }
    __syncthreads();
    s  = red[0] + red[1] + red[2] + red[3];
    sq = red[4] + red[5] + red[6] + red[7];

    float mu  = s * (1.f / D);
    float var = sq * (1.f / D) - mu * mu;
    float rr  = rsqrtf(var + 1e-12f);

    float4 G1 = *(const float4*)&g1[c];
    float4 B1 = *(const float4*)&b1[c];
    float g1a[4] = {G1.x, G1.y, G1.z, G1.w};
    float b1a[4] = {B1.x, B1.y, B1.z, B1.w};
    float v[4];
#pragma unroll
    for (int j = 0; j < 4; ++j) v[j] = (t[j] - mu) * rr * g1a[j] + b1a[j];

    float s2 = v[0] + v[1] + v[2] + v[3];
    float q2 = v[0]*v[0] + v[1]*v[1] + v[2]*v[2] + v[3]*v[3];
#pragma unroll
    for (int off = 1; off < 64; off <<= 1) {
        s2 += __shfl_xor(s2, off, 64);
        q2 += __shfl_xor(q2, off, 64);
    }
    __syncthreads();
    if (lane == 0) { red[wid] = s2; red[4 + wid] = q2; }
    __syncthreads();
    s2 = red[0] + red[1] + red[2] + red[3];
    q2 = red[4] + red[5] + red[6] + red[7];

    float mu2  = s2 * (1.f / D);
    float var2 = q2 * (1.f / D) - mu2 * mu2;
    float r2   = rsqrtf(var2 + 1e-5f);

    float4 G2 = *(const float4*)&g2[c];
    float4 B2 = *(const float4*)&b2[c];
    float g2a[4] = {G2.x, G2.y, G2.z, G2.w};
    float b2a[4] = {B2.x, B2.y, B2.z, B2.w};
    float4 o;
    float oo[4];
#pragma unroll
    for (int j = 0; j < 4; ++j) oo[j] = (v[j] - mu2) * r2 * g2a[j] + b2a[j];
    o.x = oo[0]; o.y = oo[1]; o.z = oo[2]; o.w = oo[3];
    *(float4*)&out[base] = o;
}

// ---------------------------------------------------------------------------
// ws: Qp[16M] | Kp[4M] | Vp[4M] | ctx[16M] || probe: WqTh[2M] WqTl[2M] pC[4M] flag
// aliases: att = Qp (Q dead after attn; checker runs before Wo GEMM),
//          x2 = ctx (ctx dead after Wo GEMM).
// ---------------------------------------------------------------------------
extern "C" void kernel_launch(void* const* d_in, const int* in_sizes, int n_in,
                              void* d_out, int out_size, void* d_ws, size_t ws_size,
                              hipStream_t stream)
{
    const float* qf  = (const float*)d_in[0];
    const float* vf  = (const float*)d_in[1];
    const float* Wq  = (const float*)d_in[2];
    const float* bq  = (const float*)d_in[3];
    const float* Wk  = (const float*)d_in[4];
    const float* bk  = (const float*)d_in[5];
    const float* Wv  = (const float*)d_in[6];
    const float* bv  = (const float*)d_in[7];
    const float* Wo  = (const float*)d_in[8];
    const float* bo  = (const float*)d_in[9];
    const float* g1  = (const float*)d_in[10];
    const float* b1  = (const float*)d_in[11];
    const float* g2  = (const float*)d_in[12];
    const float* b2  = (const float*)d_in[13];
    const float* Wl  = (const float*)d_in[14];
    const float* bl  = (const float*)d_in[15];

    const int Nq = in_sizes[0] / D;   // 4096
    const int Nv = in_sizes[1] / D;   // 1024

    float* ws   = (float*)d_ws;
    float* Qp   = ws;
    float* Kp   = Qp  + (size_t)Nq * D;
    float* Vp   = Kp  + (size_t)Nv * D;
    float* ctx  = Vp  + (size_t)Nv * D;
    float* att  = Qp;
    float* x2   = ctx;

    __bf16* WqTh  = (__bf16*)(ctx + (size_t)Nq * D);
    __bf16* WqTl  = WqTh + (size_t)D * D;
    float*  probeC = (float*)(WqTl + (size_t)D * D);
    float*  flag   = probeC + (size_t)D * D;

    const size_t need = (size_t)((char*)(flag + 16) - (char*)d_ws);
    const bool do_probe = (ws_size >= need);

    dim3 blk(256);
    mfma_gemm_bias<<<dim3(8, Nq / 128), blk, 0, stream>>>(qf, Wq, bq, Qp);
    mfma_gemm_bias<<<dim3(8, Nv / 128), blk, 0, stream>>>(vf, Wk, bk, Kp);
    mfma_gemm_bias<<<dim3(8, Nv / 128), blk, 0, stream>>>(vf, Wv, bv, Vp);
    attn_mfma_kernel<<<dim3(Nq / 64, NH), blk, 0, stream>>>(Qp, Kp, Vp, ctx, Nv);
    if (do_probe) {   // probe v2 GEMM on first 1024 rows; Qp still live here
        split_transpose_w<<<dim3(32, 32), blk, 0, stream>>>(Wq, WqTh, WqTl);
        mfma_gemm_v2<<<dim3(8, 8), blk, 0, stream>>>(qf, WqTh, WqTl, bq, probeC);
        check_kernel<<<dim3((D * D) / 1024), blk, 0, stream>>>(probeC, Qp, flag, 1e-3f);
    }
    mfma_gemm_bias<<<dim3(8, Nq / 128), blk, 0, stream>>>(ctx, Wo, bo, att);
    resid_dual_ln_kernel<<<dim3(Nq), blk, 0, stream>>>(att, qf, g1, b1, g2, b2, x2);
    mfma_gemm_bias<<<dim3(8, Nq / 128), blk, 0, stream>>>(x2, Wl, bl, (float*)d_out);
}

// Round 11
// 506.081 us; speedup vs baseline: 2.0854x; 1.3413x over previous
//
#include <hip/hip_runtime.h>

static constexpr int D  = 1024;
static constexpr int NH = 16;
static constexpr int DH = 64;

using bf16x8 = __attribute__((ext_vector_type(8))) __bf16;
using bf16x4 = __attribute__((ext_vector_type(4))) __bf16;
using f32x4  = __attribute__((ext_vector_type(4))) float;

// ---------------------------------------------------------------------------
// split_a: X fp32 [N] -> Xh, Xl bf16 [N] (hi/lo split). 8 elems/thread.
// ---------------------------------------------------------------------------
__global__ __launch_bounds__(256) void split_a(
    const float* __restrict__ X, __bf16* __restrict__ Xh, __bf16* __restrict__ Xl)
{
    const size_t i = ((size_t)blockIdx.x * 256 + threadIdx.x) * 8;
    float4 v0 = *(const float4*)&X[i];
    float4 v1 = *(const float4*)&X[i + 4];
    float f[8] = {v0.x, v0.y, v0.z, v0.w, v1.x, v1.y, v1.z, v1.w};
    bf16x8 h, l;
#pragma unroll
    for (int e = 0; e < 8; ++e) {
        __bf16 hi = (__bf16)f[e];
        h[e] = hi;
        l[e] = (__bf16)(f[e] - (float)hi);
    }
    *(bf16x8*)&Xh[i] = h;
    *(bf16x8*)&Xl[i] = l;
}

// ---------------------------------------------------------------------------
// split_transpose_w: W[k][n] fp32 -> Th[n][k], Tl[n][k] bf16 hi/lo, * scale.
// Grid (32,32), 256 thr, 32x32 LDS tile. (HW-verified r5, + scale arg)
// ---------------------------------------------------------------------------
__global__ __launch_bounds__(256) void split_transpose_w(
    const float* __restrict__ W, float scale,
    __bf16* __restrict__ Th, __bf16* __restrict__ Tl)
{
    __shared__ float tile[32][33];
    const int t = threadIdx.x;
    const int r = t >> 3;
    const int c4 = (t & 7) << 2;
    const int n0 = blockIdx.x * 32, k0 = blockIdx.y * 32;

    float4 v = *(const float4*)&W[(size_t)(k0 + r) * 1024 + n0 + c4];
    tile[r][c4 + 0] = v.x; tile[r][c4 + 1] = v.y;
    tile[r][c4 + 2] = v.z; tile[r][c4 + 3] = v.w;
    __syncthreads();

    float f[4] = {tile[c4 + 0][r] * scale, tile[c4 + 1][r] * scale,
                  tile[c4 + 2][r] * scale, tile[c4 + 3][r] * scale};
    bf16x4 vh, vl;
#pragma unroll
    for (int e = 0; e < 4; ++e) {
        __bf16 hi = (__bf16)f[e];
        vh[e] = hi;
        vl[e] = (__bf16)(f[e] - (float)hi);
    }
    const size_t o = (size_t)(n0 + r) * 1024 + k0 + c4;
    *(bf16x4*)&Th[o] = vh;
    *(bf16x4*)&Tl[o] = vl;
}

// ---------------------------------------------------------------------------
// GEMM v3: A pre-split [M][K] bf16 hi/lo, B pre-split pre-transposed [N][K].
// Staging = pure vector copies (v2 pattern HW-verified r5, both sides).
// Fragments/MFMA/epilogue identical to HW-verified r3 kernel.
// SPLIT_OUT: write hi/lo bf16 (for attention operands) else fp32.
// ---------------------------------------------------------------------------
template <bool SPLIT_OUT>
__global__ __launch_bounds__(256) void mfma_gemm_v3(
    const __bf16* __restrict__ Agh, const __bf16* __restrict__ Agl,
    const __bf16* __restrict__ BTh, const __bf16* __restrict__ BTl,
    const float* __restrict__ bias, float bscale,
    float* __restrict__ C, __bf16* __restrict__ Ch, __bf16* __restrict__ Cl)
{
    __shared__ alignas(16) __bf16 Ah[128][40], Al[128][40];
    __shared__ alignas(16) __bf16 Bh[128][40], Bl[128][40];   // [n-col][k]

    const int tid = threadIdx.x;
    const int bm = blockIdx.y, bn = blockIdx.x;
    const int wave = tid >> 6, lane = tid & 63;
    const int wr = wave >> 1, wc = wave & 1;
    const int li = lane & 15, g = lane >> 4;

    const int ar = tid >> 1, ac = (tid & 1) << 4;   // 2 thr/row, 16 elems each

    f32x4 acc[4][4];
#pragma unroll
    for (int m = 0; m < 4; ++m)
#pragma unroll
        for (int n = 0; n < 4; ++n) acc[m][n] = (f32x4)0.f;

    for (int k0 = 0; k0 < 1024; k0 += 32) {
        __syncthreads();
        {
            const size_t oa = (size_t)(bm * 128 + ar) * 1024 + k0 + ac;
            *(bf16x8*)&Ah[ar][ac]     = *(const bf16x8*)(Agh + oa);
            *(bf16x8*)&Ah[ar][ac + 8] = *(const bf16x8*)(Agh + oa + 8);
            *(bf16x8*)&Al[ar][ac]     = *(const bf16x8*)(Agl + oa);
            *(bf16x8*)&Al[ar][ac + 8] = *(const bf16x8*)(Agl + oa + 8);
            const size_t ob = (size_t)(bn * 128 + ar) * 1024 + k0 + ac;
            *(bf16x8*)&Bh[ar][ac]     = *(const bf16x8*)(BTh + ob);
            *(bf16x8*)&Bh[ar][ac + 8] = *(const bf16x8*)(BTh + ob + 8);
            *(bf16x8*)&Bl[ar][ac]     = *(const bf16x8*)(BTl + ob);
            *(bf16x8*)&Bl[ar][ac + 8] = *(const bf16x8*)(BTl + ob + 8);
        }
        __syncthreads();

        bf16x8 fah[4], fal[4], fbh[4], fbl[4];
#pragma unroll
        for (int m = 0; m < 4; ++m) {
            fah[m] = *(const bf16x8*)&Ah[wr * 64 + m * 16 + li][g * 8];
            fal[m] = *(const bf16x8*)&Al[wr * 64 + m * 16 + li][g * 8];
        }
#pragma unroll
        for (int n = 0; n < 4; ++n) {
            fbh[n] = *(const bf16x8*)&Bh[wc * 64 + n * 16 + li][g * 8];
            fbl[n] = *(const bf16x8*)&Bl[wc * 64 + n * 16 + li][g * 8];
        }
#pragma unroll
        for (int m = 0; m < 4; ++m)
#pragma unroll
            for (int n = 0; n < 4; ++n) {
                acc[m][n] = __builtin_amdgcn_mfma_f32_16x16x32_bf16(fah[m], fbh[n], acc[m][n], 0, 0, 0);
                acc[m][n] = __builtin_amdgcn_mfma_f32_16x16x32_bf16(fah[m], fbl[n], acc[m][n], 0, 0, 0);
                acc[m][n] = __builtin_amdgcn_mfma_f32_16x16x32_bf16(fal[m], fbh[n], acc[m][n], 0, 0, 0);
            }
    }

#pragma unroll
    for (int m = 0; m < 4; ++m)
#pragma unroll
        for (int n = 0; n < 4; ++n) {
            const int col = bn * 128 + wc * 64 + n * 16 + li;
            const float bb = bias[col] * bscale;
#pragma unroll
            for (int e = 0; e < 4; ++e) {
                const int row = bm * 128 + wr * 64 + m * 16 + g * 4 + e;
                const float val = acc[m][n][e] + bb;
                if constexpr (SPLIT_OUT) {
                    __bf16 hi = (__bf16)val;
                    Ch[(size_t)row * 1024 + col] = hi;
                    Cl[(size_t)row * 1024 + col] = (__bf16)(val - (float)hi);
                } else {
                    C[(size_t)row * 1024 + col] = val;
                }
            }
        }
}

// ---------------------------------------------------------------------------
// MFMA flash attention, operands pre-split bf16 (Q pre-scaled via Wq*0.125).
// Compute core identical to HW-verified r4 kernel; staging = vector copies.
// Grid (Nq/64, H), 4 waves; wave w owns q-strip [w*16, w*16+16).
// ---------------------------------------------------------------------------
__global__ __launch_bounds__(256) void attn_mfma_kernel(
    const __bf16* __restrict__ Qhg, const __bf16* __restrict__ Qlg,
    const __bf16* __restrict__ Khg, const __bf16* __restrict__ Klg,
    const __bf16* __restrict__ Vhg, const __bf16* __restrict__ Vlg,
    float* __restrict__ ctx, int Nv)
{
    constexpr int PT = 72;
    __shared__ alignas(16) __bf16 Qh[64][PT],  Ql[64][PT];
    __shared__ alignas(16) __bf16 KPh[64][PT], KPl[64][PT];
    __shared__ alignas(16) __bf16 Vth[64][PT], Vtl[64][PT];

    const int tid = threadIdx.x;
    const int h  = blockIdx.y;
    const int q0 = blockIdx.x * 64;
    const int wave = tid >> 6, lane = tid & 63;
    const int wr16 = wave * 16;
    const int li = lane & 15, g = lane >> 4;

    const int r = tid >> 2, c0 = (tid & 3) << 4;   // staging decomposition

    // ---- stage Q (already scaled: Wq,bq folded by 0.125) ----
    {
        const size_t o = (size_t)(q0 + r) * D + h * DH + c0;
        *(bf16x8*)&Qh[r][c0]     = *(const bf16x8*)(Qhg + o);
        *(bf16x8*)&Qh[r][c0 + 8] = *(const bf16x8*)(Qhg + o + 8);
        *(bf16x8*)&Ql[r][c0]     = *(const bf16x8*)(Qlg + o);
        *(bf16x8*)&Ql[r][c0 + 8] = *(const bf16x8*)(Qlg + o + 8);
    }

    float m_[4], l_[4];
    f32x4 o_acc[4];
#pragma unroll
    for (int e = 0; e < 4; ++e) { m_[e] = -1e30f; l_[e] = 0.f; }
#pragma unroll
    for (int n = 0; n < 4; ++n) o_acc[n] = (f32x4)0.f;

    for (int kt = 0; kt < Nv; kt += 64) {
        __syncthreads();
        {
            const size_t o = (size_t)(kt + r) * D + h * DH + c0;
            *(bf16x8*)&KPh[r][c0]     = *(const bf16x8*)(Khg + o);
            *(bf16x8*)&KPh[r][c0 + 8] = *(const bf16x8*)(Khg + o + 8);
            *(bf16x8*)&KPl[r][c0]     = *(const bf16x8*)(Klg + o);
            *(bf16x8*)&KPl[r][c0 + 8] = *(const bf16x8*)(Klg + o + 8);
            // V transposed into [d][key]
            bf16x8 vh0 = *(const bf16x8*)(Vhg + o);
            bf16x8 vh1 = *(const bf16x8*)(Vhg + o + 8);
            bf16x8 vl0 = *(const bf16x8*)(Vlg + o);
            bf16x8 vl1 = *(const bf16x8*)(Vlg + o + 8);
#pragma unroll
            for (int e = 0; e < 8; ++e) {
                Vth[c0 + e][r]     = vh0[e];
                Vth[c0 + 8 + e][r] = vh1[e];
                Vtl[c0 + e][r]     = vl0[e];
                Vtl[c0 + 8 + e][r] = vl1[e];
            }
        }
        __syncthreads();

        // ---- QK^T ----
        bf16x8 qah[2], qal[2];
#pragma unroll
        for (int kk = 0; kk < 2; ++kk) {
            qah[kk] = *(const bf16x8*)&Qh[wr16 + li][kk * 32 + g * 8];
            qal[kk] = *(const bf16x8*)&Ql[wr16 + li][kk * 32 + g * 8];
        }
        f32x4 s_acc[4];
#pragma unroll
        for (int n = 0; n < 4; ++n) s_acc[n] = (f32x4)0.f;
#pragma unroll
        for (int n = 0; n < 4; ++n)
#pragma unroll
            for (int kk = 0; kk < 2; ++kk) {
                bf16x8 kh = *(const bf16x8*)&KPh[n * 16 + li][kk * 32 + g * 8];
                bf16x8 kl = *(const bf16x8*)&KPl[n * 16 + li][kk * 32 + g * 8];
                s_acc[n] = __builtin_amdgcn_mfma_f32_16x16x32_bf16(qah[kk], kh, s_acc[n], 0, 0, 0);
                s_acc[n] = __builtin_amdgcn_mfma_f32_16x16x32_bf16(qah[kk], kl, s_acc[n], 0, 0, 0);
                s_acc[n] = __builtin_amdgcn_mfma_f32_16x16x32_bf16(qal[kk], kh, s_acc[n], 0, 0, 0);
            }

        // ---- online softmax (lane owns rows wr16+g*4+e, cols n*16+li) ----
        float rm[4];
#pragma unroll
        for (int e = 0; e < 4; ++e)
            rm[e] = fmaxf(fmaxf(s_acc[0][e], s_acc[1][e]),
                          fmaxf(s_acc[2][e], s_acc[3][e]));
#pragma unroll
        for (int off = 1; off < 16; off <<= 1)
#pragma unroll
            for (int e = 0; e < 4; ++e)
                rm[e] = fmaxf(rm[e], __shfl_xor(rm[e], off, 64));

        float resc[4], rs[4];
#pragma unroll
        for (int e = 0; e < 4; ++e) {
            float mn = fmaxf(m_[e], rm[e]);
            resc[e] = __expf(m_[e] - mn);
            m_[e] = mn;
        }
        float p[4][4];
#pragma unroll
        for (int n = 0; n < 4; ++n)
#pragma unroll
            for (int e = 0; e < 4; ++e)
                p[n][e] = __expf(s_acc[n][e] - m_[e]);
#pragma unroll
        for (int e = 0; e < 4; ++e)
            rs[e] = p[0][e] + p[1][e] + p[2][e] + p[3][e];
#pragma unroll
        for (int off = 1; off < 16; off <<= 1)
#pragma unroll
            for (int e = 0; e < 4; ++e)
                rs[e] += __shfl_xor(rs[e], off, 64);
#pragma unroll
        for (int e = 0; e < 4; ++e)
            l_[e] = l_[e] * resc[e] + rs[e];
#pragma unroll
        for (int n = 0; n < 4; ++n)
#pragma unroll
            for (int e = 0; e < 4; ++e)
                o_acc[n][e] *= resc[e];

        __syncthreads();   // all waves done reading K before P overlays it

        // ---- write P hi/lo into K's LDS space ----
#pragma unroll
        for (int n = 0; n < 4; ++n)
#pragma unroll
            for (int e = 0; e < 4; ++e) {
                const int row = wr16 + g * 4 + e;
                const int col = n * 16 + li;
                float pv = p[n][e];
                __bf16 hi = (__bf16)pv;
                KPh[row][col] = hi;
                KPl[row][col] = (__bf16)(pv - (float)hi);
            }
        __syncthreads();

        // ---- PV ----
        bf16x8 pah[2], pal[2];
#pragma unroll
        for (int kk = 0; kk < 2; ++kk) {
            pah[kk] = *(const bf16x8*)&KPh[wr16 + li][kk * 32 + g * 8];
            pal[kk] = *(const bf16x8*)&KPl[wr16 + li][kk * 32 + g * 8];
        }
#pragma unroll
        for (int n = 0; n < 4; ++n)
#pragma unroll
            for (int kk = 0; kk < 2; ++kk) {
                bf16x8 vh = *(const bf16x8*)&Vth[n * 16 + li][kk * 32 + g * 8];
                bf16x8 vl = *(const bf16x8*)&Vtl[n * 16 + li][kk * 32 + g * 8];
                o_acc[n] = __builtin_amdgcn_mfma_f32_16x16x32_bf16(pah[kk], vh, o_acc[n], 0, 0, 0);
                o_acc[n] = __builtin_amdgcn_mfma_f32_16x16x32_bf16(pah[kk], vl, o_acc[n], 0, 0, 0);
                o_acc[n] = __builtin_amdgcn_mfma_f32_16x16x32_bf16(pal[kk], vh, o_acc[n], 0, 0, 0);
            }
    }

    float inv[4];
#pragma unroll
    for (int e = 0; e < 4; ++e) inv[e] = 1.f / l_[e];
#pragma unroll
    for (int n = 0; n < 4; ++n)
#pragma unroll
        for (int e = 0; e < 4; ++e) {
            const int row = q0 + wr16 + g * 4 + e;
            const int col = h * DH + n * 16 + li;
            ctx[(size_t)row * D + col] = o_acc[n][e] * inv[e];
        }
}

// ---------------------------------------------------------------------------
// Fused residual + LN(1e-12) + LN(1e-5). One block per row. (verified)
// ---------------------------------------------------------------------------
__global__ __launch_bounds__(256) void resid_dual_ln_kernel(
    const float* __restrict__ att, const float* __restrict__ resid,
    const float* __restrict__ g1, const float* __restrict__ b1,
    const float* __restrict__ g2, const float* __restrict__ b2,
    float* __restrict__ out)
{
    const int row = blockIdx.x;
    const int tid = threadIdx.x;
    const int c = tid << 2;
    const size_t base = (size_t)row * D + c;

    float4 a = *(const float4*)&att[base];
    float4 r = *(const float4*)&resid[base];
    float t[4] = {a.x + r.x, a.y + r.y, a.z + r.z, a.w + r.w};

    __shared__ float red[8];
    const int wid = tid >> 6, lane = tid & 63;

    float s = t[0] + t[1] + t[2] + t[3];
    float sq = t[0]*t[0] + t[1]*t[1] + t[2]*t[2] + t[3]*t[3];
#pragma unroll
    for (int off = 1; off < 64; off <<= 1) {
        s  += __shfl_xor(s, off, 64);
        sq += __shfl_xor(sq, off, 64);
    }
    if (lane == 0) { red[wid] = s; red[4 + wid] = sq; }
    __syncthreads();
    s  = red[0] + red[1] + red[2] + red[3];
    sq = red[4] + red[5] + red[6] + red[7];

    float mu  = s * (1.f / D);
    float var = sq * (1.f / D) - mu * mu;
    float rr  = rsqrtf(var + 1e-12f);

    float4 G1 = *(const float4*)&g1[c];
    float4 B1 = *(const float4*)&b1[c];
    float g1a[4] = {G1.x, G1.y, G1.z, G1.w};
    float b1a[4] = {B1.x, B1.y, B1.z, B1.w};
    float v[4];
#pragma unroll
    for (int j = 0; j < 4; ++j) v[j] = (t[j] - mu) * rr * g1a[j] + b1a[j];

    float s2 = v[0] + v[1] + v[2] + v[3];
    float q2 = v[0]*v[0] + v[1]*v[1] + v[2]*v[2] + v[3]*v[3];
#pragma unroll
    for (int off = 1; off < 64; off <<= 1) {
        s2 += __shfl_xor(s2, off, 64);
        q2 += __shfl_xor(q2, off, 64);
    }
    __syncthreads();
    if (lane == 0) { red[wid] = s2; red[4 + wid] = q2; }
    __syncthreads();
    s2 = red[0] + red[1] + red[2] + red[3];
    q2 = red[4] + red[5] + red[6] + red[7];

    float mu2  = s2 * (1.f / D);
    float var2 = q2 * (1.f / D) - mu2 * mu2;
    float r2   = rsqrtf(var2 + 1e-5f);

    float4 G2 = *(const float4*)&g2[c];
    float4 B2 = *(const float4*)&b2[c];
    float g2a[4] = {G2.x, G2.y, G2.z, G2.w};
    float b2a[4] = {B2.x, B2.y, B2.z, B2.w};
    float4 o;
    float oo[4];
#pragma unroll
    for (int j = 0; j < 4; ++j) oo[j] = (v[j] - mu2) * r2 * g2a[j] + b2a[j];
    o.x = oo[0]; o.y = oo[1]; o.z = oo[2]; o.w = oo[3];
    *(float4*)&out[base] = o;
}

// ---------------------------------------------------------------------------
// ws layout (bytes), all 16 MB slots = Nq*D*4:
//   R1 [16M]: qf-split (h|l)  -> ctx-split -> x2-split   (disjoint lifetimes)
//   R2 [16M]: Q-split (h|l)   -> att fp32
//   K  [ 4M]: K-split   V [4M]: V-split   vfs [4M]: vf-split
//   W  [ 4M]: current weight split (reused 5x, sequential on stream)
// d_out doubles as scratch: ctx fp32 -> x2 fp32 -> final output.
// Total ws = 48 MB (< 58.7 MB proven available in r3).
// ---------------------------------------------------------------------------
extern "C" void kernel_launch(void* const* d_in, const int* in_sizes, int n_in,
                              void* d_out, int out_size, void* d_ws, size_t ws_size,
                              hipStream_t stream)
{
    const float* qf  = (const float*)d_in[0];
    const float* vf  = (const float*)d_in[1];
    const float* Wq  = (const float*)d_in[2];
    const float* bq  = (const float*)d_in[3];
    const float* Wk  = (const float*)d_in[4];
    const float* bk  = (const float*)d_in[5];
    const float* Wv  = (const float*)d_in[6];
    const float* bv  = (const float*)d_in[7];
    const float* Wo  = (const float*)d_in[8];
    const float* bo  = (const float*)d_in[9];
    const float* g1  = (const float*)d_in[10];
    const float* b1  = (const float*)d_in[11];
    const float* g2  = (const float*)d_in[12];
    const float* b2  = (const float*)d_in[13];
    const float* Wl  = (const float*)d_in[14];
    const float* bl  = (const float*)d_in[15];

    const int Nq = in_sizes[0] / D;   // 4096
    const int Nv = in_sizes[1] / D;   // 1024
    const size_t NQD = (size_t)Nq * D;
    const size_t NVD = (size_t)Nv * D;
    const size_t DD  = (size_t)D * D;

    char* base = (char*)d_ws;
    __bf16* R1h = (__bf16*)base;            // Nq*D
    __bf16* R1l = R1h + NQD;
    __bf16* R2h = (__bf16*)(base + NQD * 4);
    __bf16* R2l = R2h + NQD;
    float*  att = (float*)R2h;              // overlay (Q-split dead by then)
    __bf16* Ksh = (__bf16*)(base + NQD * 8);
    __bf16* Ksl = Ksh + NVD;
    __bf16* Vsh = Ksl + NVD;
    __bf16* Vsl = Vsh + NVD;
    __bf16* vfh = Vsl + NVD;
    __bf16* vfl = vfh + NVD;
    __bf16* Wth = vfl + NVD;
    __bf16* Wtl = Wth + DD;

    float* ctx = (float*)d_out;             // scratch until final GEMM
    float* x2  = (float*)d_out;

    dim3 blk(256);
    const dim3 gW(32, 32);
    const dim3 gM(8, Nq / 128), gV(8, Nv / 128);

    // activations pre-split
    split_a<<<dim3((unsigned)(NQD / 2048)), blk, 0, stream>>>(qf, R1h, R1l);
    split_a<<<dim3((unsigned)(NVD / 2048)), blk, 0, stream>>>(vf, vfh, vfl);

    // Q projection (1/sqrt(DH)=0.125 folded into Wq and bq)
    split_transpose_w<<<gW, blk, 0, stream>>>(Wq, 0.125f, Wth, Wtl);
    mfma_gemm_v3<true><<<gM, blk, 0, stream>>>(R1h, R1l, Wth, Wtl, bq, 0.125f,
                                               nullptr, R2h, R2l);
    // K projection
    split_transpose_w<<<gW, blk, 0, stream>>>(Wk, 1.f, Wth, Wtl);
    mfma_gemm_v3<true><<<gV, blk, 0, stream>>>(vfh, vfl, Wth, Wtl, bk, 1.f,
                                               nullptr, Ksh, Ksl);
    // V projection
    split_transpose_w<<<gW, blk, 0, stream>>>(Wv, 1.f, Wth, Wtl);
    mfma_gemm_v3<true><<<gV, blk, 0, stream>>>(vfh, vfl, Wth, Wtl, bv, 1.f,
                                               nullptr, Vsh, Vsl);

    // attention -> ctx (fp32, in d_out scratch)
    attn_mfma_kernel<<<dim3(Nq / 64, NH), blk, 0, stream>>>(
        R2h, R2l, Ksh, Ksl, Vsh, Vsl, ctx, Nv);

    // Wo GEMM: split ctx, then C = ctxs @ Wo + bo -> att (R2 overlay)
    split_a<<<dim3((unsigned)(NQD / 2048)), blk, 0, stream>>>(ctx, R1h, R1l);
    split_transpose_w<<<gW, blk, 0, stream>>>(Wo, 1.f, Wth, Wtl);
    mfma_gemm_v3<false><<<gM, blk, 0, stream>>>(R1h, R1l, Wth, Wtl, bo, 1.f,
                                                att, nullptr, nullptr);

    // residual + dual LN -> x2 (fp32, d_out scratch; ctx dead)
    resid_dual_ln_kernel<<<dim3(Nq), blk, 0, stream>>>(att, qf, g1, b1, g2, b2, x2);

    // final GEMM: split x2, then out = x2s @ Wl + bl -> d_out
    split_a<<<dim3((unsigned)(NQD / 2048)), blk, 0, stream>>>(x2, R1h, R1l);
    split_transpose_w<<<gW, blk, 0, stream>>>(Wl, 1.f, Wth, Wtl);
    mfma_gemm_v3<false><<<gM, blk, 0, stream>>>(R1h, R1l, Wth, Wtl, bl, 1.f,
                                                (float*)d_out, nullptr, nullptr);
}

// Round 12
// 479.809 us; speedup vs baseline: 2.1996x; 1.0548x over previous
//
#include <hip/hip_runtime.h>

static constexpr int D  = 1024;
static constexpr int NH = 16;
static constexpr int DH = 64;

using bf16x8 = __attribute__((ext_vector_type(8))) __bf16;
using bf16x4 = __attribute__((ext_vector_type(4))) __bf16;
using f32x4  = __attribute__((ext_vector_type(4))) float;

// ---------------------------------------------------------------------------
// split_a: X fp32 [N] -> Xh, Xl bf16 [N] (hi/lo split). 8 elems/thread.
// ---------------------------------------------------------------------------
__global__ __launch_bounds__(256) void split_a(
    const float* __restrict__ X, __bf16* __restrict__ Xh, __bf16* __restrict__ Xl)
{
    const size_t i = ((size_t)blockIdx.x * 256 + threadIdx.x) * 8;
    float4 v0 = *(const float4*)&X[i];
    float4 v1 = *(const float4*)&X[i + 4];
    float f[8] = {v0.x, v0.y, v0.z, v0.w, v1.x, v1.y, v1.z, v1.w};
    bf16x8 h, l;
#pragma unroll
    for (int e = 0; e < 8; ++e) {
        __bf16 hi = (__bf16)f[e];
        h[e] = hi;
        l[e] = (__bf16)(f[e] - (float)hi);
    }
    *(bf16x8*)&Xh[i] = h;
    *(bf16x8*)&Xl[i] = l;
}

// ---------------------------------------------------------------------------
// split_transpose_w: W[k][n] fp32 -> Th[n][k], Tl[n][k] bf16 hi/lo, * scale.
// Grid (32,32), 256 thr, 32x32 LDS tile. (HW-verified r5/r11)
// ---------------------------------------------------------------------------
__global__ __launch_bounds__(256) void split_transpose_w(
    const float* __restrict__ W, float scale,
    __bf16* __restrict__ Th, __bf16* __restrict__ Tl)
{
    __shared__ float tile[32][33];
    const int t = threadIdx.x;
    const int r = t >> 3;
    const int c4 = (t & 7) << 2;
    const int n0 = blockIdx.x * 32, k0 = blockIdx.y * 32;

    float4 v = *(const float4*)&W[(size_t)(k0 + r) * 1024 + n0 + c4];
    tile[r][c4 + 0] = v.x; tile[r][c4 + 1] = v.y;
    tile[r][c4 + 2] = v.z; tile[r][c4 + 3] = v.w;
    __syncthreads();

    float f[4] = {tile[c4 + 0][r] * scale, tile[c4 + 1][r] * scale,
                  tile[c4 + 2][r] * scale, tile[c4 + 3][r] * scale};
    bf16x4 vh, vl;
#pragma unroll
    for (int e = 0; e < 4; ++e) {
        __bf16 hi = (__bf16)f[e];
        vh[e] = hi;
        vl[e] = (__bf16)(f[e] - (float)hi);
    }
    const size_t o = (size_t)(n0 + r) * 1024 + k0 + c4;
    *(bf16x4*)&Th[o] = vh;
    *(bf16x4*)&Tl[o] = vl;
}

// ---------------------------------------------------------------------------
// GEMM v3 (HW-verified r11): A pre-split [M][K], B pre-split pre-transposed
// [N][K]. Pure-copy staging; r3 MFMA core; SPLIT_OUT epilogue optional.
// ---------------------------------------------------------------------------
template <bool SPLIT_OUT>
__global__ __launch_bounds__(256) void mfma_gemm_v3(
    const __bf16* __restrict__ Agh, const __bf16* __restrict__ Agl,
    const __bf16* __restrict__ BTh, const __bf16* __restrict__ BTl,
    const float* __restrict__ bias, float bscale,
    float* __restrict__ C, __bf16* __restrict__ Ch, __bf16* __restrict__ Cl)
{
    __shared__ alignas(16) __bf16 Ah[128][40], Al[128][40];
    __shared__ alignas(16) __bf16 Bh[128][40], Bl[128][40];   // [n-col][k]

    const int tid = threadIdx.x;
    const int bm = blockIdx.y, bn = blockIdx.x;
    const int wave = tid >> 6, lane = tid & 63;
    const int wr = wave >> 1, wc = wave & 1;
    const int li = lane & 15, g = lane >> 4;

    const int ar = tid >> 1, ac = (tid & 1) << 4;

    f32x4 acc[4][4];
#pragma unroll
    for (int m = 0; m < 4; ++m)
#pragma unroll
        for (int n = 0; n < 4; ++n) acc[m][n] = (f32x4)0.f;

    for (int k0 = 0; k0 < 1024; k0 += 32) {
        __syncthreads();
        {
            const size_t oa = (size_t)(bm * 128 + ar) * 1024 + k0 + ac;
            *(bf16x8*)&Ah[ar][ac]     = *(const bf16x8*)(Agh + oa);
            *(bf16x8*)&Ah[ar][ac + 8] = *(const bf16x8*)(Agh + oa + 8);
            *(bf16x8*)&Al[ar][ac]     = *(const bf16x8*)(Agl + oa);
            *(bf16x8*)&Al[ar][ac + 8] = *(const bf16x8*)(Agl + oa + 8);
            const size_t ob = (size_t)(bn * 128 + ar) * 1024 + k0 + ac;
            *(bf16x8*)&Bh[ar][ac]     = *(const bf16x8*)(BTh + ob);
            *(bf16x8*)&Bh[ar][ac + 8] = *(const bf16x8*)(BTh + ob + 8);
            *(bf16x8*)&Bl[ar][ac]     = *(const bf16x8*)(BTl + ob);
            *(bf16x8*)&Bl[ar][ac + 8] = *(const bf16x8*)(BTl + ob + 8);
        }
        __syncthreads();

        bf16x8 fah[4], fal[4], fbh[4], fbl[4];
#pragma unroll
        for (int m = 0; m < 4; ++m) {
            fah[m] = *(const bf16x8*)&Ah[wr * 64 + m * 16 + li][g * 8];
            fal[m] = *(const bf16x8*)&Al[wr * 64 + m * 16 + li][g * 8];
        }
#pragma unroll
        for (int n = 0; n < 4; ++n) {
            fbh[n] = *(const bf16x8*)&Bh[wc * 64 + n * 16 + li][g * 8];
            fbl[n] = *(const bf16x8*)&Bl[wc * 64 + n * 16 + li][g * 8];
        }
#pragma unroll
        for (int m = 0; m < 4; ++m)
#pragma unroll
            for (int n = 0; n < 4; ++n) {
                acc[m][n] = __builtin_amdgcn_mfma_f32_16x16x32_bf16(fah[m], fbh[n], acc[m][n], 0, 0, 0);
                acc[m][n] = __builtin_amdgcn_mfma_f32_16x16x32_bf16(fah[m], fbl[n], acc[m][n], 0, 0, 0);
                acc[m][n] = __builtin_amdgcn_mfma_f32_16x16x32_bf16(fal[m], fbh[n], acc[m][n], 0, 0, 0);
            }
    }

#pragma unroll
    for (int m = 0; m < 4; ++m)
#pragma unroll
        for (int n = 0; n < 4; ++n) {
            const int col = bn * 128 + wc * 64 + n * 16 + li;
            const float bb = bias[col] * bscale;
#pragma unroll
            for (int e = 0; e < 4; ++e) {
                const int row = bm * 128 + wr * 64 + m * 16 + g * 4 + e;
                const float val = acc[m][n][e] + bb;
                if constexpr (SPLIT_OUT) {
                    __bf16 hi = (__bf16)val;
                    Ch[(size_t)row * 1024 + col] = hi;
                    Cl[(size_t)row * 1024 + col] = (__bf16)(val - (float)hi);
                } else {
                    C[(size_t)row * 1024 + col] = val;
                }
            }
        }
}

// ---------------------------------------------------------------------------
// MFMA flash attention v2: Q fragments in REGISTERS (loaded once from global),
// K/P and V^T in LDS (36.9 KB -> 4 blocks/CU, was 2). Split-bf16 throughout.
// Epilogue writes hi/lo bf16 ctx directly (fused split).
// Grid (Nq/64, H), 4 waves; wave w owns q-strip [w*16, w*16+16).
// ---------------------------------------------------------------------------
__global__ __launch_bounds__(256) void attn_mfma_kernel(
    const __bf16* __restrict__ Qhg, const __bf16* __restrict__ Qlg,
    const __bf16* __restrict__ Khg, const __bf16* __restrict__ Klg,
    const __bf16* __restrict__ Vhg, const __bf16* __restrict__ Vlg,
    __bf16* __restrict__ Ch, __bf16* __restrict__ Cl, int Nv)
{
    constexpr int PT = 72;
    __shared__ alignas(16) __bf16 KPh[64][PT], KPl[64][PT];  // K tile, then P
    __shared__ alignas(16) __bf16 Vth[64][PT], Vtl[64][PT];  // V^T [d][key]

    const int tid = threadIdx.x;
    const int h  = blockIdx.y;
    const int q0 = blockIdx.x * 64;
    const int wave = tid >> 6, lane = tid & 63;
    const int wr16 = wave * 16;
    const int li = lane & 15, g = lane >> 4;

    const int r = tid >> 2, c0 = (tid & 3) << 4;   // K/V staging decomposition

    // ---- Q fragments: direct per-lane global loads (rows wr16+li) ----
    bf16x8 qah[2], qal[2];
    {
        const size_t qo = (size_t)(q0 + wr16 + li) * D + h * DH + g * 8;
        qah[0] = *(const bf16x8*)(Qhg + qo);
        qah[1] = *(const bf16x8*)(Qhg + qo + 32);
        qal[0] = *(const bf16x8*)(Qlg + qo);
        qal[1] = *(const bf16x8*)(Qlg + qo + 32);
    }

    float m_[4], l_[4];
    f32x4 o_acc[4];
#pragma unroll
    for (int e = 0; e < 4; ++e) { m_[e] = -1e30f; l_[e] = 0.f; }
#pragma unroll
    for (int n = 0; n < 4; ++n) o_acc[n] = (f32x4)0.f;

    for (int kt = 0; kt < Nv; kt += 64) {
        __syncthreads();   // prior PV reads done before K/V overwrite
        {
            const size_t o = (size_t)(kt + r) * D + h * DH + c0;
            *(bf16x8*)&KPh[r][c0]     = *(const bf16x8*)(Khg + o);
            *(bf16x8*)&KPh[r][c0 + 8] = *(const bf16x8*)(Khg + o + 8);
            *(bf16x8*)&KPl[r][c0]     = *(const bf16x8*)(Klg + o);
            *(bf16x8*)&KPl[r][c0 + 8] = *(const bf16x8*)(Klg + o + 8);
            // V transposed into [d][key]
            bf16x8 vh0 = *(const bf16x8*)(Vhg + o);
            bf16x8 vh1 = *(const bf16x8*)(Vhg + o + 8);
            bf16x8 vl0 = *(const bf16x8*)(Vlg + o);
            bf16x8 vl1 = *(const bf16x8*)(Vlg + o + 8);
#pragma unroll
            for (int e = 0; e < 8; ++e) {
                Vth[c0 + e][r]     = vh0[e];
                Vth[c0 + 8 + e][r] = vh1[e];
                Vtl[c0 + e][r]     = vl0[e];
                Vtl[c0 + 8 + e][r] = vl1[e];
            }
        }
        __syncthreads();

        // ---- QK^T ----
        f32x4 s_acc[4];
#pragma unroll
        for (int n = 0; n < 4; ++n) s_acc[n] = (f32x4)0.f;
#pragma unroll
        for (int n = 0; n < 4; ++n)
#pragma unroll
            for (int kk = 0; kk < 2; ++kk) {
                bf16x8 kh = *(const bf16x8*)&KPh[n * 16 + li][kk * 32 + g * 8];
                bf16x8 kl = *(const bf16x8*)&KPl[n * 16 + li][kk * 32 + g * 8];
                s_acc[n] = __builtin_amdgcn_mfma_f32_16x16x32_bf16(qah[kk], kh, s_acc[n], 0, 0, 0);
                s_acc[n] = __builtin_amdgcn_mfma_f32_16x16x32_bf16(qah[kk], kl, s_acc[n], 0, 0, 0);
                s_acc[n] = __builtin_amdgcn_mfma_f32_16x16x32_bf16(qal[kk], kh, s_acc[n], 0, 0, 0);
            }

        // ---- online softmax (lane owns rows wr16+g*4+e, cols n*16+li) ----
        float rm[4];
#pragma unroll
        for (int e = 0; e < 4; ++e)
            rm[e] = fmaxf(fmaxf(s_acc[0][e], s_acc[1][e]),
                          fmaxf(s_acc[2][e], s_acc[3][e]));
#pragma unroll
        for (int off = 1; off < 16; off <<= 1)
#pragma unroll
            for (int e = 0; e < 4; ++e)
                rm[e] = fmaxf(rm[e], __shfl_xor(rm[e], off, 64));

        float resc[4], rs[4];
#pragma unroll
        for (int e = 0; e < 4; ++e) {
            float mn = fmaxf(m_[e], rm[e]);
            resc[e] = __expf(m_[e] - mn);
            m_[e] = mn;
        }
        float p[4][4];
#pragma unroll
        for (int n = 0; n < 4; ++n)
#pragma unroll
            for (int e = 0; e < 4; ++e)
                p[n][e] = __expf(s_acc[n][e] - m_[e]);
#pragma unroll
        for (int e = 0; e < 4; ++e)
            rs[e] = p[0][e] + p[1][e] + p[2][e] + p[3][e];
#pragma unroll
        for (int off = 1; off < 16; off <<= 1)
#pragma unroll
            for (int e = 0; e < 4; ++e)
                rs[e] += __shfl_xor(rs[e], off, 64);
#pragma unroll
        for (int e = 0; e < 4; ++e)
            l_[e] = l_[e] * resc[e] + rs[e];
#pragma unroll
        for (int n = 0; n < 4; ++n)
#pragma unroll
            for (int e = 0; e < 4; ++e)
                o_acc[n][e] *= resc[e];

        __syncthreads();   // all waves done reading K before P overlays it

        // ---- write P hi/lo into K's LDS space ----
#pragma unroll
        for (int n = 0; n < 4; ++n)
#pragma unroll
            for (int e = 0; e < 4; ++e) {
                const int row = wr16 + g * 4 + e;
                const int col = n * 16 + li;
                float pv = p[n][e];
                __bf16 hi = (__bf16)pv;
                KPh[row][col] = hi;
                KPl[row][col] = (__bf16)(pv - (float)hi);
            }
        __syncthreads();

        // ---- PV ----
        bf16x8 pah[2], pal[2];
#pragma unroll
        for (int kk = 0; kk < 2; ++kk) {
            pah[kk] = *(const bf16x8*)&KPh[wr16 + li][kk * 32 + g * 8];
            pal[kk] = *(const bf16x8*)&KPl[wr16 + li][kk * 32 + g * 8];
        }
#pragma unroll
        for (int n = 0; n < 4; ++n)
#pragma unroll
            for (int kk = 0; kk < 2; ++kk) {
                bf16x8 vh = *(const bf16x8*)&Vth[n * 16 + li][kk * 32 + g * 8];
                bf16x8 vl = *(const bf16x8*)&Vtl[n * 16 + li][kk * 32 + g * 8];
                o_acc[n] = __builtin_amdgcn_mfma_f32_16x16x32_bf16(pah[kk], vh, o_acc[n], 0, 0, 0);
                o_acc[n] = __builtin_amdgcn_mfma_f32_16x16x32_bf16(pah[kk], vl, o_acc[n], 0, 0, 0);
                o_acc[n] = __builtin_amdgcn_mfma_f32_16x16x32_bf16(pal[kk], vh, o_acc[n], 0, 0, 0);
            }
    }

    // ---- epilogue: normalize + fused hi/lo split ----
    float inv[4];
#pragma unroll
    for (int e = 0; e < 4; ++e) inv[e] = 1.f / l_[e];
#pragma unroll
    for (int n = 0; n < 4; ++n)
#pragma unroll
        for (int e = 0; e < 4; ++e) {
            const int row = q0 + wr16 + g * 4 + e;
            const int col = h * DH + n * 16 + li;
            const float val = o_acc[n][e] * inv[e];
            __bf16 hi = (__bf16)val;
            Ch[(size_t)row * D + col] = hi;
            Cl[(size_t)row * D + col] = (__bf16)(val - (float)hi);
        }
}

// ---------------------------------------------------------------------------
// Fused residual + LN(1e-12) + LN(1e-5) + hi/lo split output. One block/row.
// ---------------------------------------------------------------------------
__global__ __launch_bounds__(256) void resid_dual_ln_kernel(
    const float* __restrict__ att, const float* __restrict__ resid,
    const float* __restrict__ g1, const float* __restrict__ b1,
    const float* __restrict__ g2, const float* __restrict__ b2,
    __bf16* __restrict__ Oh, __bf16* __restrict__ Ol)
{
    const int row = blockIdx.x;
    const int tid = threadIdx.x;
    const int c = tid << 2;
    const size_t base = (size_t)row * D + c;

    float4 a = *(const float4*)&att[base];
    float4 r = *(const float4*)&resid[base];
    float t[4] = {a.x + r.x, a.y + r.y, a.z + r.z, a.w + r.w};

    __shared__ float red[8];
    const int wid = tid >> 6, lane = tid & 63;

    float s = t[0] + t[1] + t[2] + t[3];
    float sq = t[0]*t[0] + t[1]*t[1] + t[2]*t[2] + t[3]*t[3];
#pragma unroll
    for (int off = 1; off < 64; off <<= 1) {
        s  += __shfl_xor(s, off, 64);
        sq += __shfl_xor(sq, off, 64);
    }
    if (lane == 0) { red[wid] = s; red[4 + wid] = sq; }
    __syncthreads();
    s  = red[0] + red[1] + red[2] + red[3];
    sq = red[4] + red[5] + red[6] + red[7];

    float mu  = s * (1.f / D);
    float var = sq * (1.f / D) - mu * mu;
    float rr  = rsqrtf(var + 1e-12f);

    float4 G1 = *(const float4*)&g1[c];
    float4 B1 = *(const float4*)&b1[c];
    float g1a[4] = {G1.x, G1.y, G1.z, G1.w};
    float b1a[4] = {B1.x, B1.y, B1.z, B1.w};
    float v[4];
#pragma unroll
    for (int j = 0; j < 4; ++j) v[j] = (t[j] - mu) * rr * g1a[j] + b1a[j];

    float s2 = v[0] + v[1] + v[2] + v[3];
    float q2 = v[0]*v[0] + v[1]*v[1] + v[2]*v[2] + v[3]*v[3];
#pragma unroll
    for (int off = 1; off < 64; off <<= 1) {
        s2 += __shfl_xor(s2, off, 64);
        q2 += __shfl_xor(q2, off, 64);
    }
    __syncthreads();
    if (lane == 0) { red[wid] = s2; red[4 + wid] = q2; }
    __syncthreads();
    s2 = red[0] + red[1] + red[2] + red[3];
    q2 = red[4] + red[5] + red[6] + red[7];

    float mu2  = s2 * (1.f / D);
    float var2 = q2 * (1.f / D) - mu2 * mu2;
    float r2   = rsqrtf(var2 + 1e-5f);

    float4 G2 = *(const float4*)&g2[c];
    float4 B2 = *(const float4*)&b2[c];
    float g2a[4] = {G2.x, G2.y, G2.z, G2.w};
    float b2a[4] = {B2.x, B2.y, B2.z, B2.w};
    bf16x4 oh, ol;
#pragma unroll
    for (int j = 0; j < 4; ++j) {
        float oo = (v[j] - mu2) * r2 * g2a[j] + b2a[j];
        __bf16 hi = (__bf16)oo;
        oh[j] = hi;
        ol[j] = (__bf16)(oo - (float)hi);
    }
    *(bf16x4*)&Oh[base] = oh;
    *(bf16x4*)&Ol[base] = ol;
}

// ---------------------------------------------------------------------------
// ws layout (16 MB slots = Nq*D*4):
//   R1 [16M]: qf-split -> ctx-split (attn epilogue) -> x2-split (LN epilogue)
//   R2 [16M]: Q-split  -> att fp32 (Wo GEMM output)
//   K [4M] V [4M] vfs [4M] W [4M]
// d_out written only by the final GEMM. Total ws = 48 MB.
// ---------------------------------------------------------------------------
extern "C" void kernel_launch(void* const* d_in, const int* in_sizes, int n_in,
                              void* d_out, int out_size, void* d_ws, size_t ws_size,
                              hipStream_t stream)
{
    const float* qf  = (const float*)d_in[0];
    const float* vf  = (const float*)d_in[1];
    const float* Wq  = (const float*)d_in[2];
    const float* bq  = (const float*)d_in[3];
    const float* Wk  = (const float*)d_in[4];
    const float* bk  = (const float*)d_in[5];
    const float* Wv  = (const float*)d_in[6];
    const float* bv  = (const float*)d_in[7];
    const float* Wo  = (const float*)d_in[8];
    const float* bo  = (const float*)d_in[9];
    const float* g1  = (const float*)d_in[10];
    const float* b1  = (const float*)d_in[11];
    const float* g2  = (const float*)d_in[12];
    const float* b2  = (const float*)d_in[13];
    const float* Wl  = (const float*)d_in[14];
    const float* bl  = (const float*)d_in[15];

    const int Nq = in_sizes[0] / D;   // 4096
    const int Nv = in_sizes[1] / D;   // 1024
    const size_t NQD = (size_t)Nq * D;
    const size_t NVD = (size_t)Nv * D;
    const size_t DD  = (size_t)D * D;

    char* base = (char*)d_ws;
    __bf16* R1h = (__bf16*)base;            // Nq*D
    __bf16* R1l = R1h + NQD;
    __bf16* R2h = (__bf16*)(base + NQD * 4);
    __bf16* R2l = R2h + NQD;
    float*  att = (float*)R2h;              // overlay (Q-split dead by then)
    __bf16* Ksh = (__bf16*)(base + NQD * 8);
    __bf16* Ksl = Ksh + NVD;
    __bf16* Vsh = Ksl + NVD;
    __bf16* Vsl = Vsh + NVD;
    __bf16* vfh = Vsl + NVD;
    __bf16* vfl = vfh + NVD;
    __bf16* Wth = vfl + NVD;
    __bf16* Wtl = Wth + DD;

    dim3 blk(256);
    const dim3 gW(32, 32);
    const dim3 gM(8, Nq / 128), gV(8, Nv / 128);

    // activations pre-split
    split_a<<<dim3((unsigned)(NQD / 2048)), blk, 0, stream>>>(qf, R1h, R1l);
    split_a<<<dim3((unsigned)(NVD / 2048)), blk, 0, stream>>>(vf, vfh, vfl);

    // Q projection (1/sqrt(DH)=0.125 folded into Wq and bq)
    split_transpose_w<<<gW, blk, 0, stream>>>(Wq, 0.125f, Wth, Wtl);
    mfma_gemm_v3<true><<<gM, blk, 0, stream>>>(R1h, R1l, Wth, Wtl, bq, 0.125f,
                                               nullptr, R2h, R2l);
    // K projection
    split_transpose_w<<<gW, blk, 0, stream>>>(Wk, 1.f, Wth, Wtl);
    mfma_gemm_v3<true><<<gV, blk, 0, stream>>>(vfh, vfl, Wth, Wtl, bk, 1.f,
                                               nullptr, Ksh, Ksl);
    // V projection
    split_transpose_w<<<gW, blk, 0, stream>>>(Wv, 1.f, Wth, Wtl);
    mfma_gemm_v3<true><<<gV, blk, 0, stream>>>(vfh, vfl, Wth, Wtl, bv, 1.f,
                                               nullptr, Vsh, Vsl);

    // attention -> ctx split directly into R1 (qf-split dead after Q proj)
    attn_mfma_kernel<<<dim3(Nq / 64, NH), blk, 0, stream>>>(
        R2h, R2l, Ksh, Ksl, Vsh, Vsl, R1h, R1l, Nv);

    // Wo GEMM: C = ctx-split @ Wo + bo -> att fp32 (R2 overlay)
    split_transpose_w<<<gW, blk, 0, stream>>>(Wo, 1.f, Wth, Wtl);
    mfma_gemm_v3<false><<<gM, blk, 0, stream>>>(R1h, R1l, Wth, Wtl, bo, 1.f,
                                                att, nullptr, nullptr);

    // residual + dual LN -> x2-split directly into R1 (ctx-split dead)
    resid_dual_ln_kernel<<<dim3(Nq), blk, 0, stream>>>(att, qf, g1, b1, g2, b2,
                                                       R1h, R1l);

    // final GEMM: out = x2-split @ Wl + bl -> d_out
    split_transpose_w<<<gW, blk, 0, stream>>>(Wl, 1.f, Wth, Wtl);
    mfma_gemm_v3<false><<<gM, blk, 0, stream>>>(R1h, R1l, Wth, Wtl, bl, 1.f,
                                                (float*)d_out, nullptr, nullptr);
}

// Round 15
// 412.594 us; speedup vs baseline: 2.5579x; 1.1629x over previous
//
#include <hip/hip_runtime.h>

static constexpr int D  = 1024;
static constexpr int NH = 16;
static constexpr int DH = 64;

using bf16x8 = __attribute__((ext_vector_type(8))) __bf16;
using bf16x4 = __attribute__((ext_vector_type(4))) __bf16;
using f32x4  = __attribute__((ext_vector_type(4))) float;

// ---------------------------------------------------------------------------
// split_a: X fp32 [N] -> Xh, Xl bf16 [N] (hi/lo split). 8 elems/thread.
// ---------------------------------------------------------------------------
__global__ __launch_bounds__(256) void split_a(
    const float* __restrict__ X, __bf16* __restrict__ Xh, __bf16* __restrict__ Xl)
{
    const size_t i = ((size_t)blockIdx.x * 256 + threadIdx.x) * 8;
    float4 v0 = *(const float4*)&X[i];
    float4 v1 = *(const float4*)&X[i + 4];
    float f[8] = {v0.x, v0.y, v0.z, v0.w, v1.x, v1.y, v1.z, v1.w};
    bf16x8 h, l;
#pragma unroll
    for (int e = 0; e < 8; ++e) {
        __bf16 hi = (__bf16)f[e];
        h[e] = hi;
        l[e] = (__bf16)(f[e] - (float)hi);
    }
    *(bf16x8*)&Xh[i] = h;
    *(bf16x8*)&Xl[i] = l;
}

// ---------------------------------------------------------------------------
// split_transpose_w: W[k][n] fp32 -> Th[n][k], Tl[n][k] bf16 hi/lo, * scale.
// ---------------------------------------------------------------------------
__global__ __launch_bounds__(256) void split_transpose_w(
    const float* __restrict__ W, float scale,
    __bf16* __restrict__ Th, __bf16* __restrict__ Tl)
{
    __shared__ float tile[32][33];
    const int t = threadIdx.x;
    const int r = t >> 3;
    const int c4 = (t & 7) << 2;
    const int n0 = blockIdx.x * 32, k0 = blockIdx.y * 32;

    float4 v = *(const float4*)&W[(size_t)(k0 + r) * 1024 + n0 + c4];
    tile[r][c4 + 0] = v.x; tile[r][c4 + 1] = v.y;
    tile[r][c4 + 2] = v.z; tile[r][c4 + 3] = v.w;
    __syncthreads();

    float f[4] = {tile[c4 + 0][r] * scale, tile[c4 + 1][r] * scale,
                  tile[c4 + 2][r] * scale, tile[c4 + 3][r] * scale};
    bf16x4 vh, vl;
#pragma unroll
    for (int e = 0; e < 4; ++e) {
        __bf16 hi = (__bf16)f[e];
        vh[e] = hi;
        vl[e] = (__bf16)(f[e] - (float)hi);
    }
    const size_t o = (size_t)(n0 + r) * 1024 + k0 + c4;
    *(bf16x4*)&Th[o] = vh;
    *(bf16x4*)&Tl[o] = vl;
}

// ---------------------------------------------------------------------------
// GEMM v4 = v3 (HW-verified r11/r12) + register prefetch of next k-tile
// (r0-verified pattern): loads for tile k+1 issue during tile k's MFMAs.
// ---------------------------------------------------------------------------
template <bool SPLIT_OUT>
__global__ __launch_bounds__(256) void mfma_gemm_v4(
    const __bf16* __restrict__ Agh, const __bf16* __restrict__ Agl,
    const __bf16* __restrict__ BTh, const __bf16* __restrict__ BTl,
    const float* __restrict__ bias, float bscale,
    float* __restrict__ C, __bf16* __restrict__ Ch, __bf16* __restrict__ Cl)
{
    __shared__ alignas(16) __bf16 Ah[128][40], Al[128][40];
    __shared__ alignas(16) __bf16 Bh[128][40], Bl[128][40];   // [n-col][k]

    const int tid = threadIdx.x;
    const int bm = blockIdx.y, bn = blockIdx.x;
    const int wave = tid >> 6, lane = tid & 63;
    const int wr = wave >> 1, wc = wave & 1;
    const int li = lane & 15, g = lane >> 4;

    const int ar = tid >> 1, ac = (tid & 1) << 4;

    f32x4 acc[4][4];
#pragma unroll
    for (int m = 0; m < 4; ++m)
#pragma unroll
        for (int n = 0; n < 4; ++n) acc[m][n] = (f32x4)0.f;

    const size_t oaBase = (size_t)(bm * 128 + ar) * 1024 + ac;
    const size_t obBase = (size_t)(bn * 128 + ar) * 1024 + ac;

    bf16x8 rah[2], ral[2], rbh[2], rbl[2];
    // prologue: load tile k0=0
    rah[0] = *(const bf16x8*)(Agh + oaBase);
    rah[1] = *(const bf16x8*)(Agh + oaBase + 8);
    ral[0] = *(const bf16x8*)(Agl + oaBase);
    ral[1] = *(const bf16x8*)(Agl + oaBase + 8);
    rbh[0] = *(const bf16x8*)(BTh + obBase);
    rbh[1] = *(const bf16x8*)(BTh + obBase + 8);
    rbl[0] = *(const bf16x8*)(BTl + obBase);
    rbl[1] = *(const bf16x8*)(BTl + obBase + 8);

    for (int k0 = 0; k0 < 1024; k0 += 32) {
        __syncthreads();
        *(bf16x8*)&Ah[ar][ac]     = rah[0];
        *(bf16x8*)&Ah[ar][ac + 8] = rah[1];
        *(bf16x8*)&Al[ar][ac]     = ral[0];
        *(bf16x8*)&Al[ar][ac + 8] = ral[1];
        *(bf16x8*)&Bh[ar][ac]     = rbh[0];
        *(bf16x8*)&Bh[ar][ac + 8] = rbh[1];
        *(bf16x8*)&Bl[ar][ac]     = rbl[0];
        *(bf16x8*)&Bl[ar][ac + 8] = rbl[1];
        __syncthreads();

        if (k0 + 32 < 1024) {   // prefetch next tile (hidden under MFMAs)
            const size_t oa = oaBase + k0 + 32;
            const size_t ob = obBase + k0 + 32;
            rah[0] = *(const bf16x8*)(Agh + oa);
            rah[1] = *(const bf16x8*)(Agh + oa + 8);
            ral[0] = *(const bf16x8*)(Agl + oa);
            ral[1] = *(const bf16x8*)(Agl + oa + 8);
            rbh[0] = *(const bf16x8*)(BTh + ob);
            rbh[1] = *(const bf16x8*)(BTh + ob + 8);
            rbl[0] = *(const bf16x8*)(BTl + ob);
            rbl[1] = *(const bf16x8*)(BTl + ob + 8);
        }

        bf16x8 fah[4], fal[4], fbh[4], fbl[4];
#pragma unroll
        for (int m = 0; m < 4; ++m) {
            fah[m] = *(const bf16x8*)&Ah[wr * 64 + m * 16 + li][g * 8];
            fal[m] = *(const bf16x8*)&Al[wr * 64 + m * 16 + li][g * 8];
        }
#pragma unroll
        for (int n = 0; n < 4; ++n) {
            fbh[n] = *(const bf16x8*)&Bh[wc * 64 + n * 16 + li][g * 8];
            fbl[n] = *(const bf16x8*)&Bl[wc * 64 + n * 16 + li][g * 8];
        }
#pragma unroll
        for (int m = 0; m < 4; ++m)
#pragma unroll
            for (int n = 0; n < 4; ++n) {
                acc[m][n] = __builtin_amdgcn_mfma_f32_16x16x32_bf16(fah[m], fbh[n], acc[m][n], 0, 0, 0);
                acc[m][n] = __builtin_amdgcn_mfma_f32_16x16x32_bf16(fah[m], fbl[n], acc[m][n], 0, 0, 0);
                acc[m][n] = __builtin_amdgcn_mfma_f32_16x16x32_bf16(fal[m], fbh[n], acc[m][n], 0, 0, 0);
            }
    }

#pragma unroll
    for (int m = 0; m < 4; ++m)
#pragma unroll
        for (int n = 0; n < 4; ++n) {
            const int col = bn * 128 + wc * 64 + n * 16 + li;
            const float bb = bias[col] * bscale;
#pragma unroll
            for (int e = 0; e < 4; ++e) {
                const int row = bm * 128 + wr * 64 + m * 16 + g * 4 + e;
                const float val = acc[m][n][e] + bb;
                if constexpr (SPLIT_OUT) {
                    __bf16 hi = (__bf16)val;
                    Ch[(size_t)row * 1024 + col] = hi;
                    Cl[(size_t)row * 1024 + col] = (__bf16)(val - (float)hi);
                } else {
                    C[(size_t)row * 1024 + col] = val;
                }
            }
        }
}

// ---------------------------------------------------------------------------
// Fused K+V projection: grid.z selects {B1,bias1,C1} or {B2,bias2,C2}.
// Same v4 body, SPLIT_OUT always. Doubles resident blocks vs 2 launches.
// ---------------------------------------------------------------------------
__global__ __launch_bounds__(256) void mfma_gemm_kv(
    const __bf16* __restrict__ Agh, const __bf16* __restrict__ Agl,
    const __bf16* __restrict__ B1h, const __bf16* __restrict__ B1l,
    const float* __restrict__ bias1, __bf16* __restrict__ C1h, __bf16* __restrict__ C1l,
    const __bf16* __restrict__ B2h, const __bf16* __restrict__ B2l,
    const float* __restrict__ bias2, __bf16* __restrict__ C2h, __bf16* __restrict__ C2l)
{
    const bool z = (blockIdx.z != 0);
    const __bf16* BTh = z ? B2h : B1h;
    const __bf16* BTl = z ? B2l : B1l;
    const float*  bias = z ? bias2 : bias1;
    __bf16* Ch = z ? C2h : C1h;
    __bf16* Cl = z ? C2l : C1l;

    __shared__ alignas(16) __bf16 Ah[128][40], Al[128][40];
    __shared__ alignas(16) __bf16 Bh[128][40], Bl[128][40];

    const int tid = threadIdx.x;
    const int bm = blockIdx.y, bn = blockIdx.x;
    const int wave = tid >> 6, lane = tid & 63;
    const int wr = wave >> 1, wc = wave & 1;
    const int li = lane & 15, g = lane >> 4;

    const int ar = tid >> 1, ac = (tid & 1) << 4;

    f32x4 acc[4][4];
#pragma unroll
    for (int m = 0; m < 4; ++m)
#pragma unroll
        for (int n = 0; n < 4; ++n) acc[m][n] = (f32x4)0.f;

    const size_t oaBase = (size_t)(bm * 128 + ar) * 1024 + ac;
    const size_t obBase = (size_t)(bn * 128 + ar) * 1024 + ac;

    bf16x8 rah[2], ral[2], rbh[2], rbl[2];
    rah[0] = *(const bf16x8*)(Agh + oaBase);
    rah[1] = *(const bf16x8*)(Agh + oaBase + 8);
    ral[0] = *(const bf16x8*)(Agl + oaBase);
    ral[1] = *(const bf16x8*)(Agl + oaBase + 8);
    rbh[0] = *(const bf16x8*)(BTh + obBase);
    rbh[1] = *(const bf16x8*)(BTh + obBase + 8);
    rbl[0] = *(const bf16x8*)(BTl + obBase);
    rbl[1] = *(const bf16x8*)(BTl + obBase + 8);

    for (int k0 = 0; k0 < 1024; k0 += 32) {
        __syncthreads();
        *(bf16x8*)&Ah[ar][ac]     = rah[0];
        *(bf16x8*)&Ah[ar][ac + 8] = rah[1];
        *(bf16x8*)&Al[ar][ac]     = ral[0];
        *(bf16x8*)&Al[ar][ac + 8] = ral[1];
        *(bf16x8*)&Bh[ar][ac]     = rbh[0];
        *(bf16x8*)&Bh[ar][ac + 8] = rbh[1];
        *(bf16x8*)&Bl[ar][ac]     = rbl[0];
        *(bf16x8*)&Bl[ar][ac + 8] = rbl[1];
        __syncthreads();

        if (k0 + 32 < 1024) {
            const size_t oa = oaBase + k0 + 32;
            const size_t ob = obBase + k0 + 32;
            rah[0] = *(const bf16x8*)(Agh + oa);
            rah[1] = *(const bf16x8*)(Agh + oa + 8);
            ral[0] = *(const bf16x8*)(Agl + oa);
            ral[1] = *(const bf16x8*)(Agl + oa + 8);
            rbh[0] = *(const bf16x8*)(BTh + ob);
            rbh[1] = *(const bf16x8*)(BTh + ob + 8);
            rbl[0] = *(const bf16x8*)(BTl + ob);
            rbl[1] = *(const bf16x8*)(BTl + ob + 8);
        }

        bf16x8 fah[4], fal[4], fbh[4], fbl[4];
#pragma unroll
        for (int m = 0; m < 4; ++m) {
            fah[m] = *(const bf16x8*)&Ah[wr * 64 + m * 16 + li][g * 8];
            fal[m] = *(const bf16x8*)&Al[wr * 64 + m * 16 + li][g * 8];
        }
#pragma unroll
        for (int n = 0; n < 4; ++n) {
            fbh[n] = *(const bf16x8*)&Bh[wc * 64 + n * 16 + li][g * 8];
            fbl[n] = *(const bf16x8*)&Bl[wc * 64 + n * 16 + li][g * 8];
        }
#pragma unroll
        for (int m = 0; m < 4; ++m)
#pragma unroll
            for (int n = 0; n < 4; ++n) {
                acc[m][n] = __builtin_amdgcn_mfma_f32_16x16x32_bf16(fah[m], fbh[n], acc[m][n], 0, 0, 0);
                acc[m][n] = __builtin_amdgcn_mfma_f32_16x16x32_bf16(fah[m], fbl[n], acc[m][n], 0, 0, 0);
                acc[m][n] = __builtin_amdgcn_mfma_f32_16x16x32_bf16(fal[m], fbh[n], acc[m][n], 0, 0, 0);
            }
    }

#pragma unroll
    for (int m = 0; m < 4; ++m)
#pragma unroll
        for (int n = 0; n < 4; ++n) {
            const int col = bn * 128 + wc * 64 + n * 16 + li;
            const float bb = bias[col];
#pragma unroll
            for (int e = 0; e < 4; ++e) {
                const int row = bm * 128 + wr * 64 + m * 16 + g * 4 + e;
                const float val = acc[m][n][e] + bb;
                __bf16 hi = (__bf16)val;
                Ch[(size_t)row * 1024 + col] = hi;
                Cl[(size_t)row * 1024 + col] = (__bf16)(val - (float)hi);
            }
        }
}

// ---------------------------------------------------------------------------
// MFMA flash attention v3: Q in registers; K/P, V^T in LDS (36.9 KB,
// 4 blocks/CU); + T14 async-stage: next K/V tile prefetched into registers
// during QK^T/softmax/PV. Epilogue writes hi/lo bf16 ctx (fused split).
// ---------------------------------------------------------------------------
__global__ __launch_bounds__(256) void attn_mfma_kernel(
    const __bf16* __restrict__ Qhg, const __bf16* __restrict__ Qlg,
    const __bf16* __restrict__ Khg, const __bf16* __restrict__ Klg,
    const __bf16* __restrict__ Vhg, const __bf16* __restrict__ Vlg,
    __bf16* __restrict__ Ch, __bf16* __restrict__ Cl, int Nv)
{
    constexpr int PT = 72;
    __shared__ alignas(16) __bf16 KPh[64][PT], KPl[64][PT];  // K tile, then P
    __shared__ alignas(16) __bf16 Vth[64][PT], Vtl[64][PT];  // V^T [d][key]

    const int tid = threadIdx.x;
    const int h  = blockIdx.y;
    const int q0 = blockIdx.x * 64;
    const int wave = tid >> 6, lane = tid & 63;
    const int wr16 = wave * 16;
    const int li = lane & 15, g = lane >> 4;

    const int r = tid >> 2, c0 = (tid & 3) << 4;   // K/V staging decomposition
    const size_t stBase = (size_t)r * D + h * DH + c0;

    // ---- Q fragments: direct per-lane global loads ----
    bf16x8 qah[2], qal[2];
    {
        const size_t qo = (size_t)(q0 + wr16 + li) * D + h * DH + g * 8;
        qah[0] = *(const bf16x8*)(Qhg + qo);
        qah[1] = *(const bf16x8*)(Qhg + qo + 32);
        qal[0] = *(const bf16x8*)(Qlg + qo);
        qal[1] = *(const bf16x8*)(Qlg + qo + 32);
    }

    // ---- prefetch regs for K/V tile ----
    bf16x8 rkh[2], rkl[2], rvh[2], rvl[2];
    {
        const size_t o = stBase;   // kt = 0
        rkh[0] = *(const bf16x8*)(Khg + o);
        rkh[1] = *(const bf16x8*)(Khg + o + 8);
        rkl[0] = *(const bf16x8*)(Klg + o);
        rkl[1] = *(const bf16x8*)(Klg + o + 8);
        rvh[0] = *(const bf16x8*)(Vhg + o);
        rvh[1] = *(const bf16x8*)(Vhg + o + 8);
        rvl[0] = *(const bf16x8*)(Vlg + o);
        rvl[1] = *(const bf16x8*)(Vlg + o + 8);
    }

    float m_[4], l_[4];
    f32x4 o_acc[4];
#pragma unroll
    for (int e = 0; e < 4; ++e) { m_[e] = -1e30f; l_[e] = 0.f; }
#pragma unroll
    for (int n = 0; n < 4; ++n) o_acc[n] = (f32x4)0.f;

    for (int kt = 0; kt < Nv; kt += 64) {
        __syncthreads();   // prior tile's LDS reads done before overwrite
        // ---- LDS writes from prefetched regs ----
        *(bf16x8*)&KPh[r][c0]     = rkh[0];
        *(bf16x8*)&KPh[r][c0 + 8] = rkh[1];
        *(bf16x8*)&KPl[r][c0]     = rkl[0];
        *(bf16x8*)&KPl[r][c0 + 8] = rkl[1];
#pragma unroll
        for (int e = 0; e < 8; ++e) {
            Vth[c0 + e][r]     = rvh[0][e];
            Vth[c0 + 8 + e][r] = rvh[1][e];
            Vtl[c0 + e][r]     = rvl[0][e];
            Vtl[c0 + 8 + e][r] = rvl[1][e];
        }
        __syncthreads();

        if (kt + 64 < Nv) {   // prefetch next tile (hidden under compute)
            const size_t o = stBase + (size_t)(kt + 64) * D;
            rkh[0] = *(const bf16x8*)(Khg + o);
            rkh[1] = *(const bf16x8*)(Khg + o + 8);
            rkl[0] = *(const bf16x8*)(Klg + o);
            rkl[1] = *(const bf16x8*)(Klg + o + 8);
            rvh[0] = *(const bf16x8*)(Vhg + o);
            rvh[1] = *(const bf16x8*)(Vhg + o + 8);
            rvl[0] = *(const bf16x8*)(Vlg + o);
            rvl[1] = *(const bf16x8*)(Vlg + o + 8);
        }

        // ---- QK^T ----
        f32x4 s_acc[4];
#pragma unroll
        for (int n = 0; n < 4; ++n) s_acc[n] = (f32x4)0.f;
#pragma unroll
        for (int n = 0; n < 4; ++n)
#pragma unroll
            for (int kk = 0; kk < 2; ++kk) {
                bf16x8 kh = *(const bf16x8*)&KPh[n * 16 + li][kk * 32 + g * 8];
                bf16x8 kl = *(const bf16x8*)&KPl[n * 16 + li][kk * 32 + g * 8];
                s_acc[n] = __builtin_amdgcn_mfma_f32_16x16x32_bf16(qah[kk], kh, s_acc[n], 0, 0, 0);
                s_acc[n] = __builtin_amdgcn_mfma_f32_16x16x32_bf16(qah[kk], kl, s_acc[n], 0, 0, 0);
                s_acc[n] = __builtin_amdgcn_mfma_f32_16x16x32_bf16(qal[kk], kh, s_acc[n], 0, 0, 0);
            }

        // ---- online softmax ----
        float rm[4];
#pragma unroll
        for (int e = 0; e < 4; ++e)
            rm[e] = fmaxf(fmaxf(s_acc[0][e], s_acc[1][e]),
                          fmaxf(s_acc[2][e], s_acc[3][e]));
#pragma unroll
        for (int off = 1; off < 16; off <<= 1)
#pragma unroll
            for (int e = 0; e < 4; ++e)
                rm[e] = fmaxf(rm[e], __shfl_xor(rm[e], off, 64));

        float resc[4], rs[4];
#pragma unroll
        for (int e = 0; e < 4; ++e) {
            float mn = fmaxf(m_[e], rm[e]);
            resc[e] = __expf(m_[e] - mn);
            m_[e] = mn;
        }
        float p[4][4];
#pragma unroll
        for (int n = 0; n < 4; ++n)
#pragma unroll
            for (int e = 0; e < 4; ++e)
                p[n][e] = __expf(s_acc[n][e] - m_[e]);
#pragma unroll
        for (int e = 0; e < 4; ++e)
            rs[e] = p[0][e] + p[1][e] + p[2][e] + p[3][e];
#pragma unroll
        for (int off = 1; off < 16; off <<= 1)
#pragma unroll
            for (int e = 0; e < 4; ++e)
                rs[e] += __shfl_xor(rs[e], off, 64);
#pragma unroll
        for (int e = 0; e < 4; ++e)
            l_[e] = l_[e] * resc[e] + rs[e];
#pragma unroll
        for (int n = 0; n < 4; ++n)
#pragma unroll
            for (int e = 0; e < 4; ++e)
                o_acc[n][e] *= resc[e];

        __syncthreads();   // all waves done reading K before P overlays it

        // ---- write P hi/lo into K's LDS space ----
#pragma unroll
        for (int n = 0; n < 4; ++n)
#pragma unroll
            for (int e = 0; e < 4; ++e) {
                const int row = wr16 + g * 4 + e;
                const int col = n * 16 + li;
                float pv = p[n][e];
                __bf16 hi = (__bf16)pv;
                KPh[row][col] = hi;
                KPl[row][col] = (__bf16)(pv - (float)hi);
            }
        __syncthreads();

        // ---- PV ----
        bf16x8 pah[2], pal[2];
#pragma unroll
        for (int kk = 0; kk < 2; ++kk) {
            pah[kk] = *(const bf16x8*)&KPh[wr16 + li][kk * 32 + g * 8];
            pal[kk] = *(const bf16x8*)&KPl[wr16 + li][kk * 32 + g * 8];
        }
#pragma unroll
        for (int n = 0; n < 4; ++n)
#pragma unroll
            for (int kk = 0; kk < 2; ++kk) {
                bf16x8 vh = *(const bf16x8*)&Vth[n * 16 + li][kk * 32 + g * 8];
                bf16x8 vl = *(const bf16x8*)&Vtl[n * 16 + li][kk * 32 + g * 8];
                o_acc[n] = __builtin_amdgcn_mfma_f32_16x16x32_bf16(pah[kk], vh, o_acc[n], 0, 0, 0);
                o_acc[n] = __builtin_amdgcn_mfma_f32_16x16x32_bf16(pah[kk], vl, o_acc[n], 0, 0, 0);
                o_acc[n] = __builtin_amdgcn_mfma_f32_16x16x32_bf16(pal[kk], vh, o_acc[n], 0, 0, 0);
            }
    }

    // ---- epilogue: normalize + fused hi/lo split ----
    float inv[4];
#pragma unroll
    for (int e = 0; e < 4; ++e) inv[e] = 1.f / l_[e];
#pragma unroll
    for (int n = 0; n < 4; ++n)
#pragma unroll
        for (int e = 0; e < 4; ++e) {
            const int row = q0 + wr16 + g * 4 + e;
            const int col = h * DH + n * 16 + li;
            const float val = o_acc[n][e] * inv[e];
            __bf16 hi = (__bf16)val;
            Ch[(size_t)row * D + col] = hi;
            Cl[(size_t)row * D + col] = (__bf16)(val - (float)hi);
        }
}

// ---------------------------------------------------------------------------
// Fused residual + LN(1e-12) + LN(1e-5) + hi/lo split output. One block/row.
// ---------------------------------------------------------------------------
__global__ __launch_bounds__(256) void resid_dual_ln_kernel(
    const float* __restrict__ att, const float* __restrict__ resid,
    const float* __restrict__ g1, const float* __restrict__ b1,
    const float* __restrict__ g2, const float* __restrict__ b2,
    __bf16* __restrict__ Oh, __bf16* __restrict__ Ol)
{
    const int row = blockIdx.x;
    const int tid = threadIdx.x;
    const int c = tid << 2;
    const size_t base = (size_t)row * D + c;

    float4 a = *(const float4*)&att[base];
    float4 r = *(const float4*)&resid[base];
    float t[4] = {a.x + r.x, a.y + r.y, a.z + r.z, a.w + r.w};

    __shared__ float red[8];
    const int wid = tid >> 6, lane = tid & 63;

    float s = t[0] + t[1] + t[2] + t[3];
    float sq = t[0]*t[0] + t[1]*t[1] + t[2]*t[2] + t[3]*t[3];
#pragma unroll
    for (int off = 1; off < 64; off <<= 1) {
        s  += __shfl_xor(s, off, 64);
        sq += __shfl_xor(sq, off, 64);
    }
    if (lane == 0) { red[wid] = s; red[4 + wid] = sq; }
    __syncthreads();
    s  = red[0] + red[1] + red[2] + red[3];
    sq = red[4] + red[5] + red[6] + red[7];

    float mu  = s * (1.f / D);
    float var = sq * (1.f / D) - mu * mu;
    float rr  = rsqrtf(var + 1e-12f);

    float4 G1 = *(const float4*)&g1[c];
    float4 B1 = *(const float4*)&b1[c];
    float g1a[4] = {G1.x, G1.y, G1.z, G1.w};
    float b1a[4] = {B1.x, B1.y, B1.z, B1.w};
    float v[4];
#pragma unroll
    for (int j = 0; j < 4; ++j) v[j] = (t[j] - mu) * rr * g1a[j] + b1a[j];

    float s2 = v[0] + v[1] + v[2] + v[3];
    float q2 = v[0]*v[0] + v[1]*v[1] + v[2]*v[2] + v[3]*v[3];
#pragma unroll
    for (int off = 1; off < 64; off <<= 1) {
        s2 += __shfl_xor(s2, off, 64);
        q2 += __shfl_xor(q2, off, 64);
    }
    __syncthreads();
    if (lane == 0) { red[wid] = s2; red[4 + wid] = q2; }
    __syncthreads();
    s2 = red[0] + red[1] + red[2] + red[3];
    q2 = red[4] + red[5] + red[6] + red[7];

    float mu2  = s2 * (1.f / D);
    float var2 = q2 * (1.f / D) - mu2 * mu2;
    float r2   = rsqrtf(var2 + 1e-5f);

    float4 G2 = *(const float4*)&g2[c];
    float4 B2 = *(const float4*)&b2[c];
    float g2a[4] = {G2.x, G2.y, G2.z, G2.w};
    float b2a[4] = {B2.x, B2.y, B2.z, B2.w};
    bf16x4 oh, ol;
#pragma unroll
    for (int j = 0; j < 4; ++j) {
        float oo = (v[j] - mu2) * r2 * g2a[j] + b2a[j];
        __bf16 hi = (__bf16)oo;
        oh[j] = hi;
        ol[j] = (__bf16)(oo - (float)hi);
    }
    *(bf16x4*)&Oh[base] = oh;
    *(bf16x4*)&Ol[base] = ol;
}

// ---------------------------------------------------------------------------
// ws layout (16 MB slots = Nq*D*4):
//   R1 [16M]: qf-split -> ctx-split (attn epilogue) -> x2-split (LN epilogue)
//   R2 [16M]: Q-split  -> att fp32 (Wo GEMM output)
//   K [4M] V [4M] vfs [4M] W1 [4M] W2 [4M] W3 [4M]   total = 56 MB (<58.7 proven)
// W1: Wq -> Wo -> Wl (sequential reuse). W2: Wk. W3: Wv.
// ---------------------------------------------------------------------------
extern "C" void kernel_launch(void* const* d_in, const int* in_sizes, int n_in,
                              void* d_out, int out_size, void* d_ws, size_t ws_size,
                              hipStream_t stream)
{
    const float* qf  = (const float*)d_in[0];
    const float* vf  = (const float*)d_in[1];
    const float* Wq  = (const float*)d_in[2];
    const float* bq  = (const float*)d_in[3];
    const float* Wk  = (const float*)d_in[4];
    const float* bk  = (const float*)d_in[5];
    const float* Wv  = (const float*)d_in[6];
    const float* bv  = (const float*)d_in[7];
    const float* Wo  = (const float*)d_in[8];
    const float* bo  = (const float*)d_in[9];
    const float* g1  = (const float*)d_in[10];
    const float* b1  = (const float*)d_in[11];
    const float* g2  = (const float*)d_in[12];
    const float* b2  = (const float*)d_in[13];
    const float* Wl  = (const float*)d_in[14];
    const float* bl  = (const float*)d_in[15];

    const int Nq = in_sizes[0] / D;   // 4096
    const int Nv = in_sizes[1] / D;   // 1024
    const size_t NQD = (size_t)Nq * D;
    const size_t NVD = (size_t)Nv * D;
    const size_t DD  = (size_t)D * D;

    char* base = (char*)d_ws;
    __bf16* R1h = (__bf16*)base;            // Nq*D
    __bf16* R1l = R1h + NQD;
    __bf16* R2h = (__bf16*)(base + NQD * 4);
    __bf16* R2l = R2h + NQD;
    float*  att = (float*)R2h;              // overlay (Q-split dead by then)
    __bf16* Ksh = (__bf16*)(base + NQD * 8);
    __bf16* Ksl = Ksh + NVD;
    __bf16* Vsh = Ksl + NVD;
    __bf16* Vsl = Vsh + NVD;
    __bf16* vfh = Vsl + NVD;
    __bf16* vfl = vfh + NVD;
    __bf16* W1h = vfl + NVD;
    __bf16* W1l = W1h + DD;
    __bf16* W2h = W1l + DD;
    __bf16* W2l = W2h + DD;
    __bf16* W3h = W2l + DD;
    __bf16* W3l = W3h + DD;

    dim3 blk(256);
    const dim3 gW(32, 32);
    const dim3 gM(8, Nq / 128);
    const dim3 gKV(8, Nv / 128, 2);

    // activations pre-split
    split_a<<<dim3((unsigned)(NQD / 2048)), blk, 0, stream>>>(qf, R1h, R1l);
    split_a<<<dim3((unsigned)(NVD / 2048)), blk, 0, stream>>>(vf, vfh, vfl);

    // weight splits (Wq scaled by 1/sqrt(DH)=0.125; Wk, Wv unscaled)
    split_transpose_w<<<gW, blk, 0, stream>>>(Wq, 0.125f, W1h, W1l);
    split_transpose_w<<<gW, blk, 0, stream>>>(Wk, 1.f,    W2h, W2l);
    split_transpose_w<<<gW, blk, 0, stream>>>(Wv, 1.f,    W3h, W3l);

    // Q projection
    mfma_gemm_v4<true><<<gM, blk, 0, stream>>>(R1h, R1l, W1h, W1l, bq, 0.125f,
                                               nullptr, R2h, R2l);
    // fused K+V projections (grid.z selects)
    mfma_gemm_kv<<<gKV, blk, 0, stream>>>(vfh, vfl,
                                          W2h, W2l, bk, Ksh, Ksl,
                                          W3h, W3l, bv, Vsh, Vsl);

    // attention -> ctx split directly into R1 (qf-split dead after Q proj)
    attn_mfma_kernel<<<dim3(Nq / 64, NH), blk, 0, stream>>>(
        R2h, R2l, Ksh, Ksl, Vsh, Vsl, R1h, R1l, Nv);

    // Wo GEMM: C = ctx-split @ Wo + bo -> att fp32 (R2 overlay)
    split_transpose_w<<<gW, blk, 0, stream>>>(Wo, 1.f, W1h, W1l);
    mfma_gemm_v4<false><<<gM, blk, 0, stream>>>(R1h, R1l, W1h, W1l, bo, 1.f,
                                                att, nullptr, nullptr);

    // residual + dual LN -> x2-split directly into R1 (ctx-split dead)
    resid_dual_ln_kernel<<<dim3(Nq), blk, 0, stream>>>(att, qf, g1, b1, g2, b2,
                                                       R1h, R1l);

    // final GEMM: out = x2-split @ Wl + bl -> d_out
    split_transpose_w<<<gW, blk, 0, stream>>>(Wl, 1.f, W1h, W1l);
    mfma_gemm_v4<false><<<gM, blk, 0, stream>>>(R1h, R1l, W1h, W1l, bl, 1.f,
                                                (float*)d_out, nullptr, nullptr);
}